// Round 1
// baseline (693.866 us; speedup 1.0000x reference)
//
#include <hip/hip_runtime.h>
#include <hip/hip_bf16.h>

// GCN 2-layer: N=100000 nodes, E=1.6M edges, IN=HID=128, OUT=64, fp32.
// Pipeline: deg histogram -> scan -> CSR fill -> GEMM1 -> agg1(+b1,relu)
//           -> GEMM2 -> agg2(+b2) -> d_out.

#define IN_F  128
#define HID_F 128
#define OUT_F 64

// ---------------- degree histogram ----------------
__global__ void k_deg(const int* __restrict__ dst, int E, int* __restrict__ deg) {
    int i = blockIdx.x * blockDim.x + threadIdx.x;
    if (i < E) atomicAdd(&deg[dst[i]], 1);
}

// ---------------- hierarchical exclusive scan ----------------
// Stage 1: per-1024-chunk scan (256 threads x 4 items), chunk-exclusive out + chunk sums.
__global__ void k_scan1(const int* __restrict__ deg, int N,
                        int* __restrict__ excl, int* __restrict__ blocksum) {
    __shared__ int s[256];
    int t = threadIdx.x;
    int base = blockIdx.x * 1024;
    int idx0 = base + t * 4;
    int v[4];
    int sum = 0;
#pragma unroll
    for (int j = 0; j < 4; j++) {
        int i = idx0 + j;
        v[j] = (i < N) ? deg[i] : 0;
        sum += v[j];
    }
    s[t] = sum;
    __syncthreads();
    for (int ofs = 1; ofs < 256; ofs <<= 1) {
        int add = (t >= ofs) ? s[t - ofs] : 0;
        __syncthreads();
        s[t] += add;
        __syncthreads();
    }
    int e = s[t] - sum;  // exclusive within chunk
#pragma unroll
    for (int j = 0; j < 4; j++) {
        int i = idx0 + j;
        if (i < N) excl[i] = e;
        e += v[j];
    }
    if (t == 255) blocksum[blockIdx.x] = s[255];
}

// Stage 2: scan the (<=1024) chunk sums in one block -> exclusive.
__global__ void k_scan2(int* __restrict__ blocksum, int B) {
    __shared__ int s[1024];
    int t = threadIdx.x;
    int v = (t < B) ? blocksum[t] : 0;
    s[t] = v;
    __syncthreads();
    for (int ofs = 1; ofs < 1024; ofs <<= 1) {
        int add = (t >= ofs) ? s[t - ofs] : 0;
        __syncthreads();
        s[t] += add;
        __syncthreads();
    }
    if (t < B) blocksum[t] = s[t] - v;
}

// Stage 3: finalize offsets, cursor copy, dinv.
__global__ void k_finalize(const int* __restrict__ deg, int* __restrict__ off,
                           int* __restrict__ cursor, float* __restrict__ dinv,
                           const int* __restrict__ blockoff, int N, int E) {
    int i = blockIdx.x * blockDim.x + threadIdx.x;
    if (i < N) {
        int o = off[i] + blockoff[i >> 10];
        off[i] = o;
        cursor[i] = o;
        dinv[i] = rsqrtf((float)deg[i] + 1.0f);
    }
    if (i == 0) off[N] = E;
}

// ---------------- CSR fill ----------------
__global__ void k_fill(const int* __restrict__ src, const int* __restrict__ dst, int E,
                       int* __restrict__ cursor, int* __restrict__ col) {
    int i = blockIdx.x * blockDim.x + threadIdx.x;
    if (i < E) {
        int d = dst[i];
        int pos = atomicAdd(&cursor[d], 1);
        col[pos] = src[i];
    }
}

// ---------------- fp32 GEMM: H[n,m] = sum_k X[n,k]*W[m,k], K=128 ----------------
// block tile 64x64, 256 threads (16x16), thread tile 4x4, K chunk 32.
#define TILE_K 32
__global__ __launch_bounds__(256) void k_gemm(const float* __restrict__ X,
                                              const float* __restrict__ W,
                                              float* __restrict__ H, int N, int M) {
    __shared__ float As[TILE_K][64];  // As[k][n]
    __shared__ float Bs[TILE_K][64];  // Bs[k][m]
    int t = threadIdx.x;
    int tx = t & 15, ty = t >> 4;
    int n0 = blockIdx.x * 64;
    int m0 = blockIdx.y * 64;
    float acc[4][4] = {{0.f}};
    for (int kc = 0; kc < 128; kc += TILE_K) {
#pragma unroll
        for (int r = 0; r < 2; r++) {
            int q = t + r * 256;       // 0..511 float4 slots
            int node = q >> 3;
            int k4 = q & 7;
            int gn = n0 + node;
            float4 v = make_float4(0.f, 0.f, 0.f, 0.f);
            if (gn < N) v = *(const float4*)(X + (size_t)gn * 128 + kc + k4 * 4);
            As[k4 * 4 + 0][node] = v.x;
            As[k4 * 4 + 1][node] = v.y;
            As[k4 * 4 + 2][node] = v.z;
            As[k4 * 4 + 3][node] = v.w;
        }
#pragma unroll
        for (int r = 0; r < 2; r++) {
            int q = t + r * 256;
            int m = q >> 3;
            int k4 = q & 7;
            float4 v = *(const float4*)(W + (size_t)(m0 + m) * 128 + kc + k4 * 4);
            Bs[k4 * 4 + 0][m] = v.x;
            Bs[k4 * 4 + 1][m] = v.y;
            Bs[k4 * 4 + 2][m] = v.z;
            Bs[k4 * 4 + 3][m] = v.w;
        }
        __syncthreads();
#pragma unroll
        for (int kk = 0; kk < TILE_K; kk++) {
            float4 a = *(const float4*)&As[kk][ty * 4];
            float4 b = *(const float4*)&Bs[kk][tx * 4];
            float av[4] = {a.x, a.y, a.z, a.w};
            float bv[4] = {b.x, b.y, b.z, b.w};
#pragma unroll
            for (int i = 0; i < 4; i++)
#pragma unroll
                for (int j = 0; j < 4; j++) acc[i][j] += av[i] * bv[j];
        }
        __syncthreads();
    }
#pragma unroll
    for (int i = 0; i < 4; i++) {
        int gn = n0 + ty * 4 + i;
        if (gn < N) {
            float4 v = make_float4(acc[i][0], acc[i][1], acc[i][2], acc[i][3]);
            *(float4*)(H + (size_t)gn * M + m0 + tx * 4) = v;
        }
    }
}

// ---------------- aggregation: one wave per node ----------------
// out[i,f] = bias[f] + dinv_i^2*h[i,f] + sum_{e in CSR(i)} dinv_i*dinv[src]*h[src,f]
template <int F, bool RELU>
__global__ __launch_bounds__(256) void k_agg(const float* __restrict__ h,
                                             const int* __restrict__ off,
                                             const int* __restrict__ col,
                                             const float* __restrict__ dinv,
                                             const float* __restrict__ bias,
                                             float* __restrict__ out, int N) {
    int wave = threadIdx.x >> 6;
    int lane = threadIdx.x & 63;
    int node = blockIdx.x * 4 + wave;
    if (node >= N) return;
    constexpr int V = F / 64;
    float di = dinv[node];
    const float* hrow = h + (size_t)node * F;
    float acc[V];
#pragma unroll
    for (int v = 0; v < V; v++) acc[v] = di * di * hrow[lane * V + v];
    int e0 = off[node], e1 = off[node + 1];
    for (int e = e0; e < e1; e++) {
        int s = col[e];
        float w = di * dinv[s];
        const float* hs = h + (size_t)s * F;
#pragma unroll
        for (int v = 0; v < V; v++) acc[v] += w * hs[lane * V + v];
    }
    float* orow = out + (size_t)node * F;
#pragma unroll
    for (int v = 0; v < V; v++) {
        float r = acc[v] + bias[lane * V + v];
        if (RELU) r = fmaxf(r, 0.f);
        orow[lane * V + v] = r;
    }
}

extern "C" void kernel_launch(void* const* d_in, const int* in_sizes, int n_in,
                              void* d_out, int out_size, void* d_ws, size_t ws_size,
                              hipStream_t stream) {
    const float* x  = (const float*)d_in[0];
    const float* W1 = (const float*)d_in[1];
    const float* b1 = (const float*)d_in[2];
    const float* W2 = (const float*)d_in[3];
    const float* b2 = (const float*)d_in[4];
    const int*   ei = (const int*)d_in[5];

    int N = in_sizes[0] / IN_F;
    int E = in_sizes[5] / 2;
    const int* src = ei;
    const int* dst = ei + E;

    // workspace layout
    size_t woff = 0;
    auto alloc = [&](size_t bytes) {
        void* p = (char*)d_ws + woff;
        woff += (bytes + 255) & ~(size_t)255;
        return p;
    };
    int*   deg      = (int*)alloc((size_t)N * 4);
    int*   offs     = (int*)alloc((size_t)(N + 1) * 4);
    int*   cursor   = (int*)alloc((size_t)N * 4);
    int*   blocksum = (int*)alloc(1024 * 4);
    int*   col      = (int*)alloc((size_t)E * 4);
    float* dinv     = (float*)alloc((size_t)N * 4);
    float* h1       = (float*)alloc((size_t)N * HID_F * 4);
    float* h1r      = (float*)alloc((size_t)N * HID_F * 4);
    float* h2       = h1;  // h1 dead after agg1; reuse for layer-2 GEMM output
    float* outp     = (float*)d_out;

    hipMemsetAsync(deg, 0, (size_t)N * 4, stream);

    int eb = (E + 255) / 256;
    k_deg<<<eb, 256, 0, stream>>>(dst, E, deg);

    int chunks = (N + 1023) / 1024;
    k_scan1<<<chunks, 256, 0, stream>>>(deg, N, offs, blocksum);
    k_scan2<<<1, 1024, 0, stream>>>(blocksum, chunks);
    k_finalize<<<(N + 255) / 256, 256, 0, stream>>>(deg, offs, cursor, dinv, blocksum, N, E);
    k_fill<<<eb, 256, 0, stream>>>(src, dst, E, cursor, col);

    // layer 1
    {
        dim3 grid((N + 63) / 64, HID_F / 64);
        k_gemm<<<grid, 256, 0, stream>>>(x, W1, h1, N, HID_F);
        k_agg<HID_F, true><<<(N + 3) / 4, 256, 0, stream>>>(h1, offs, col, dinv, b1, h1r, N);
    }
    // layer 2
    {
        dim3 grid((N + 63) / 64, OUT_F / 64);
        k_gemm<<<grid, 256, 0, stream>>>(h1r, W2, h2, N, OUT_F);
        k_agg<OUT_F, false><<<(N + 3) / 4, 256, 0, stream>>>(h2, offs, col, dinv, b2, outp, N);
    }
}

// Round 2
// 474.110 us; speedup vs baseline: 1.4635x; 1.4635x over previous
//
#include <hip/hip_runtime.h>
#include <hip/hip_bf16.h>

// GCN 2-layer, N=100000, E=1.6M, 128->128->64.
// Round 2: bf16 feature tables (halve gather bytes), MFMA GEMMs,
// 4-way unrolled gather loop for memory-level parallelism.

#define IN_F  128
#define HID_F 128
#define OUT_F 64

typedef __bf16 bf16_t;
typedef __bf16 bf16x2 __attribute__((ext_vector_type(2)));
typedef __bf16 bf16x8 __attribute__((ext_vector_type(8)));
typedef float  f32x4  __attribute__((ext_vector_type(4)));

// ---------------- degree histogram ----------------
__global__ void k_deg(const int* __restrict__ dst, int E, int* __restrict__ deg) {
    int i = blockIdx.x * blockDim.x + threadIdx.x;
    if (i < E) atomicAdd(&deg[dst[i]], 1);
}

// ---------------- hierarchical exclusive scan ----------------
__global__ void k_scan1(const int* __restrict__ deg, int N,
                        int* __restrict__ excl, int* __restrict__ blocksum) {
    __shared__ int s[256];
    int t = threadIdx.x;
    int base = blockIdx.x * 1024;
    int idx0 = base + t * 4;
    int v[4];
    int sum = 0;
#pragma unroll
    for (int j = 0; j < 4; j++) {
        int i = idx0 + j;
        v[j] = (i < N) ? deg[i] : 0;
        sum += v[j];
    }
    s[t] = sum;
    __syncthreads();
    for (int ofs = 1; ofs < 256; ofs <<= 1) {
        int add = (t >= ofs) ? s[t - ofs] : 0;
        __syncthreads();
        s[t] += add;
        __syncthreads();
    }
    int e = s[t] - sum;
#pragma unroll
    for (int j = 0; j < 4; j++) {
        int i = idx0 + j;
        if (i < N) excl[i] = e;
        e += v[j];
    }
    if (t == 255) blocksum[blockIdx.x] = s[255];
}

__global__ void k_scan2(int* __restrict__ blocksum, int B) {
    __shared__ int s[1024];
    int t = threadIdx.x;
    int v = (t < B) ? blocksum[t] : 0;
    s[t] = v;
    __syncthreads();
    for (int ofs = 1; ofs < 1024; ofs <<= 1) {
        int add = (t >= ofs) ? s[t - ofs] : 0;
        __syncthreads();
        s[t] += add;
        __syncthreads();
    }
    if (t < B) blocksum[t] = s[t] - v;
}

__global__ void k_finalize(const int* __restrict__ deg, int* __restrict__ off,
                           int* __restrict__ cursor, float* __restrict__ dinv,
                           const int* __restrict__ blockoff, int N, int E) {
    int i = blockIdx.x * blockDim.x + threadIdx.x;
    if (i < N) {
        int o = off[i] + blockoff[i >> 10];
        off[i] = o;
        cursor[i] = o;
        dinv[i] = rsqrtf((float)deg[i] + 1.0f);
    }
    if (i == 0) off[N] = E;
}

__global__ void k_fill(const int* __restrict__ src, const int* __restrict__ dst, int E,
                       int* __restrict__ cursor, int* __restrict__ col) {
    int i = blockIdx.x * blockDim.x + threadIdx.x;
    if (i < E) {
        int d = dst[i];
        int pos = atomicAdd(&cursor[d], 1);
        col[pos] = src[i];
    }
}

// ---------------- fp32 -> bf16 convert ----------------
__global__ void k_f2b(const float* __restrict__ a, bf16_t* __restrict__ o, int n) {
    int i = blockIdx.x * blockDim.x + threadIdx.x;
    if (i < n) o[i] = (bf16_t)a[i];
}

// ---------------- MFMA GEMM: H[n, m] = sum_k X[n,k] * W[m,k], K=128 ----------------
// Block: 4 waves x 32 rows = 128 rows. Wave covers all NCOL cols.
// A fragment (16x16x32): lane holds A[m=lane&15][k=quad*8+j], j=0..7.
// B fragment: lane holds B[k=quad*8+j][n=lane&15] = W[lane&15][quad*8+j] (row-major W!).
// D: col=lane&15, row=quad*4+reg.
template <int NCOL, typename TIN>
__global__ __launch_bounds__(256) void k_gemm_mfma(const TIN* __restrict__ X,
                                                   const bf16_t* __restrict__ W,
                                                   bf16_t* __restrict__ H, int N) {
    constexpr int CT = NCOL / 16;
    int wv = threadIdx.x >> 6, lane = threadIdx.x & 63;
    int quad = lane >> 4, l16 = lane & 15;
    int row0 = blockIdx.x * 128 + wv * 32;
    f32x4 acc[2][CT] = {};
#pragma unroll
    for (int ks = 0; ks < 4; ks++) {
        int k0 = ks * 32 + quad * 8;
        bf16x8 a[2];
#pragma unroll
        for (int rt = 0; rt < 2; rt++) {
            int r = row0 + rt * 16 + l16;
            if (r >= N) r = N - 1;  // clamp; stores guarded below
            const TIN* p = X + (size_t)r * 128 + k0;
            if constexpr (sizeof(TIN) == 4) {
                f32x4 x0 = *(const f32x4*)p;
                f32x4 x1 = *(const f32x4*)(p + 4);
                bf16x8 t;
                t[0] = (bf16_t)x0[0]; t[1] = (bf16_t)x0[1];
                t[2] = (bf16_t)x0[2]; t[3] = (bf16_t)x0[3];
                t[4] = (bf16_t)x1[0]; t[5] = (bf16_t)x1[1];
                t[6] = (bf16_t)x1[2]; t[7] = (bf16_t)x1[3];
                a[rt] = t;
            } else {
                a[rt] = *(const bf16x8*)p;
            }
        }
#pragma unroll
        for (int ct = 0; ct < CT; ct++) {
            bf16x8 b = *(const bf16x8*)(W + (size_t)(ct * 16 + l16) * 128 + k0);
#pragma unroll
            for (int rt = 0; rt < 2; rt++)
                acc[rt][ct] = __builtin_amdgcn_mfma_f32_16x16x32_bf16(a[rt], b, acc[rt][ct], 0, 0, 0);
        }
    }
#pragma unroll
    for (int rt = 0; rt < 2; rt++)
#pragma unroll
        for (int r4 = 0; r4 < 4; r4++) {
            int r = row0 + rt * 16 + quad * 4 + r4;
            if (r < N) {
#pragma unroll
                for (int ct = 0; ct < CT; ct++)
                    H[(size_t)r * NCOL + ct * 16 + l16] = (bf16_t)acc[rt][ct][r4];
            }
        }
}

// ---------------- aggregation: one wave per node, 4-way edge unroll ----------------
// out[i,f] = bias[f] + di^2*h[i,f] + sum_e di*dinv[src]*h[src,f]
template <int F, bool RELU, typename TOUT>
__global__ __launch_bounds__(256) void k_agg(const bf16_t* __restrict__ h,
                                             const int* __restrict__ off,
                                             const int* __restrict__ col,
                                             const float* __restrict__ dinv,
                                             const float* __restrict__ bias,
                                             TOUT* __restrict__ out, int N) {
    constexpr int V = F / 64;
    int wave = threadIdx.x >> 6;
    int lane = threadIdx.x & 63;
    int node = blockIdx.x * 4 + wave;
    if (node >= N) return;
    float di = dinv[node];
    float acc[V];
    {
        const bf16_t* p = h + (size_t)node * F + lane * V;
        if constexpr (V == 2) {
            bf16x2 r = *(const bf16x2*)p;
            acc[0] = di * di * (float)r[0];
            acc[1] = di * di * (float)r[1];
        } else {
            acc[0] = di * di * (float)p[0];
        }
    }
    int e0 = off[node], e1 = off[node + 1];
    int e = e0;
    for (; e + 4 <= e1; e += 4) {
        int s0 = col[e + 0], s1 = col[e + 1], s2 = col[e + 2], s3 = col[e + 3];
        const bf16_t* p0 = h + (size_t)s0 * F + lane * V;
        const bf16_t* p1 = h + (size_t)s1 * F + lane * V;
        const bf16_t* p2 = h + (size_t)s2 * F + lane * V;
        const bf16_t* p3 = h + (size_t)s3 * F + lane * V;
        float w0 = di * dinv[s0], w1 = di * dinv[s1];
        float w2 = di * dinv[s2], w3 = di * dinv[s3];
        if constexpr (V == 2) {
            bf16x2 r0 = *(const bf16x2*)p0;
            bf16x2 r1 = *(const bf16x2*)p1;
            bf16x2 r2 = *(const bf16x2*)p2;
            bf16x2 r3 = *(const bf16x2*)p3;
            acc[0] += w0 * (float)r0[0] + w1 * (float)r1[0] + w2 * (float)r2[0] + w3 * (float)r3[0];
            acc[1] += w0 * (float)r0[1] + w1 * (float)r1[1] + w2 * (float)r2[1] + w3 * (float)r3[1];
        } else {
            float r0 = (float)p0[0], r1 = (float)p1[0], r2 = (float)p2[0], r3 = (float)p3[0];
            acc[0] += w0 * r0 + w1 * r1 + w2 * r2 + w3 * r3;
        }
    }
    for (; e < e1; e++) {
        int s = col[e];
        float w = di * dinv[s];
        const bf16_t* p = h + (size_t)s * F + lane * V;
        if constexpr (V == 2) {
            bf16x2 r = *(const bf16x2*)p;
            acc[0] += w * (float)r[0];
            acc[1] += w * (float)r[1];
        } else {
            acc[0] += w * (float)p[0];
        }
    }
#pragma unroll
    for (int v = 0; v < V; v++) {
        float r = acc[v] + bias[lane * V + v];
        if (RELU) r = fmaxf(r, 0.f);
        if constexpr (sizeof(TOUT) == 2)
            out[(size_t)node * F + lane * V + v] = (TOUT)r;
        else
            out[(size_t)node * F + lane * V + v] = (TOUT)r;
    }
}

extern "C" void kernel_launch(void* const* d_in, const int* in_sizes, int n_in,
                              void* d_out, int out_size, void* d_ws, size_t ws_size,
                              hipStream_t stream) {
    const float* x  = (const float*)d_in[0];
    const float* W1 = (const float*)d_in[1];
    const float* b1 = (const float*)d_in[2];
    const float* W2 = (const float*)d_in[3];
    const float* b2 = (const float*)d_in[4];
    const int*   ei = (const int*)d_in[5];

    int N = in_sizes[0] / IN_F;
    int E = in_sizes[5] / 2;
    const int* src = ei;
    const int* dst = ei + E;

    size_t woff = 0;
    auto alloc = [&](size_t bytes) {
        void* p = (char*)d_ws + woff;
        woff += (bytes + 255) & ~(size_t)255;
        return p;
    };
    int*    deg      = (int*)alloc((size_t)N * 4);
    int*    offs     = (int*)alloc((size_t)(N + 1) * 4);
    int*    cursor   = (int*)alloc((size_t)N * 4);
    int*    blocksum = (int*)alloc(1024 * 4);
    int*    col      = (int*)alloc((size_t)E * 4);
    float*  dinv     = (float*)alloc((size_t)N * 4);
    bf16_t* W1b      = (bf16_t*)alloc((size_t)HID_F * IN_F * 2);
    bf16_t* W2b      = (bf16_t*)alloc((size_t)OUT_F * HID_F * 2);
    bf16_t* h1       = (bf16_t*)alloc((size_t)N * HID_F * 2);
    bf16_t* h1r      = (bf16_t*)alloc((size_t)N * HID_F * 2);
    bf16_t* h2       = h1;  // h1 dead after agg1
    float*  outp     = (float*)d_out;

    hipMemsetAsync(deg, 0, (size_t)N * 4, stream);

    // weight conversions (independent of CSR chain)
    k_f2b<<<(HID_F * IN_F + 255) / 256, 256, 0, stream>>>(W1, W1b, HID_F * IN_F);
    k_f2b<<<(OUT_F * HID_F + 255) / 256, 256, 0, stream>>>(W2, W2b, OUT_F * HID_F);

    int eb = (E + 255) / 256;
    k_deg<<<eb, 256, 0, stream>>>(dst, E, deg);
    int chunks = (N + 1023) / 1024;
    k_scan1<<<chunks, 256, 0, stream>>>(deg, N, offs, blocksum);
    k_scan2<<<1, 1024, 0, stream>>>(blocksum, chunks);
    k_finalize<<<(N + 255) / 256, 256, 0, stream>>>(deg, offs, cursor, dinv, blocksum, N, E);
    k_fill<<<eb, 256, 0, stream>>>(src, dst, E, cursor, col);

    int gemm_blocks = (N + 127) / 128;
    int agg_blocks  = (N + 3) / 4;

    // layer 1: GEMM (fp32 x -> bf16 h1), agg (+b1, relu) -> bf16 h1r
    k_gemm_mfma<HID_F, float><<<gemm_blocks, 256, 0, stream>>>(x, W1b, h1, N);
    k_agg<HID_F, true, bf16_t><<<agg_blocks, 256, 0, stream>>>(h1, offs, col, dinv, b1, h1r, N);

    // layer 2: GEMM (bf16 h1r -> bf16 h2), agg (+b2) -> fp32 out
    k_gemm_mfma<OUT_F, bf16_t><<<gemm_blocks, 256, 0, stream>>>(h1r, W2b, h2, N);
    k_agg<OUT_F, false, float><<<agg_blocks, 256, 0, stream>>>(h2, offs, col, dinv, b2, outp, N);
}

// Round 3
// 384.718 us; speedup vs baseline: 1.8036x; 1.2324x over previous
//
#include <hip/hip_runtime.h>
#include <hip/hip_bf16.h>

// GCN 2-layer, N=100000, E=1.6M, 128->128->64.
// Round 3: bucketed CSR build (all scattered writes in LDS), replaces the
// atomic-scatter k_deg/k_fill chain (127us fill with 106MB write-allocate).
// GEMMs: bf16 MFMA direct-from-global. Agg: wave/node gather, 8-way unroll.

#define IN_F  128
#define HID_F 128
#define OUT_F 64

#define NPB     128    // nodes per bucket (dst>>7)
#define MAXBKT  1024   // LDS histogram capacity (N<=131072)
#define CHUNK   16384  // edges per workgroup in hist/part
#define CAP     4096   // col staging capacity per bucket (mean ~2047)

typedef __bf16 bf16_t;
typedef __bf16 bf16x2 __attribute__((ext_vector_type(2)));
typedef __bf16 bf16x8 __attribute__((ext_vector_type(8)));
typedef float  f32x4  __attribute__((ext_vector_type(4)));

// ---------------- pass A: bucket histogram ----------------
__global__ __launch_bounds__(256) void k_hist(const int* __restrict__ dst, int E,
                                              int* __restrict__ bcnt, int NBKT) {
    __shared__ int cnt[MAXBKT];
    for (int i = threadIdx.x; i < NBKT; i += 256) cnt[i] = 0;
    __syncthreads();
    int base = blockIdx.x * CHUNK;
    for (int i = threadIdx.x; i < CHUNK; i += 256) {
        int e = base + i;
        if (e < E) atomicAdd(&cnt[dst[e] >> 7], 1);
    }
    __syncthreads();
    for (int i = threadIdx.x; i < NBKT; i += 256)
        if (cnt[i]) atomicAdd(&bcnt[i], cnt[i]);
}

// ---------------- pass B: scan bucket counts (1 block) ----------------
__global__ __launch_bounds__(1024) void k_bscan(const int* __restrict__ bcnt,
                                                int* __restrict__ boff,
                                                int* __restrict__ bcur, int NBKT) {
    __shared__ int s[1024];
    int t = threadIdx.x;
    int v = (t < NBKT) ? bcnt[t] : 0;
    s[t] = v;
    __syncthreads();
    for (int ofs = 1; ofs < 1024; ofs <<= 1) {
        int add = (t >= ofs) ? s[t - ofs] : 0;
        __syncthreads();
        s[t] += add;
        __syncthreads();
    }
    if (t < NBKT) {
        int e = s[t] - v;
        boff[t] = e;
        bcur[t] = e;
    }
    if (t == 1023) boff[NBKT] = s[1023];  // total = E
}

// ---------------- pass C: partition edges into buckets ----------------
// packed = (dst&127)<<17 | src   (src < 2^17, dst_local < 2^7)
__global__ __launch_bounds__(256) void k_part(const int* __restrict__ src,
                                              const int* __restrict__ dst, int E,
                                              int* __restrict__ bcur,
                                              unsigned* __restrict__ part, int NBKT) {
    __shared__ int cnt[MAXBKT];
    __shared__ int base[MAXBKT];
    for (int i = threadIdx.x; i < NBKT; i += 256) cnt[i] = 0;
    __syncthreads();
    int cbase = blockIdx.x * CHUNK;
    for (int i = threadIdx.x; i < CHUNK; i += 256) {
        int e = cbase + i;
        if (e < E) atomicAdd(&cnt[dst[e] >> 7], 1);
    }
    __syncthreads();
    for (int i = threadIdx.x; i < NBKT; i += 256) {
        int c = cnt[i];
        base[i] = c ? atomicAdd(&bcur[i], c) : 0;
        cnt[i] = 0;  // reuse as local cursor
    }
    __syncthreads();
    for (int i = threadIdx.x; i < CHUNK; i += 256) {
        int e = cbase + i;
        if (e < E) {
            int d = dst[e];
            int b = d >> 7;
            int lp = atomicAdd(&cnt[b], 1);
            part[base[b] + lp] = (unsigned)src[e] | ((unsigned)(d & 127) << 17);
        }
    }
}

// ---------------- pass D: per-bucket CSR finalize (LDS-local) ----------------
__global__ __launch_bounds__(256) void k_bucket(const unsigned* __restrict__ part,
                                                const int* __restrict__ boff,
                                                int* __restrict__ offs,
                                                int* __restrict__ col,
                                                float* __restrict__ dinv,
                                                int N, int E) {
    __shared__ int lcnt[NPB];
    __shared__ int lexc[NPB];
    __shared__ int lcur[NPB];
    __shared__ int stage[CAP];
    int b = blockIdx.x;
    int t = threadIdx.x;
    int node0 = b * NPB;
    int nb = min(NPB, N - node0);
    int e0 = boff[b], e1 = boff[b + 1];
    int cnt = e1 - e0;
    if (t < NPB) lcnt[t] = 0;
    __syncthreads();
    for (int i = t; i < cnt; i += 256)
        atomicAdd(&lcnt[part[e0 + i] >> 17], 1);
    __syncthreads();
    if (t < NPB) lexc[t] = lcnt[t];
    __syncthreads();
    for (int ofs = 1; ofs < NPB; ofs <<= 1) {
        int add = (t >= ofs && t < NPB) ? lexc[t - ofs] : 0;
        __syncthreads();
        if (t < NPB) lexc[t] += add;
        __syncthreads();
    }
    if (t < NPB) {
        int ex = lexc[t] - lcnt[t];  // exclusive scan
        lcur[t] = ex;
        if (t < nb) {
            offs[node0 + t] = e0 + ex;
            dinv[node0 + t] = rsqrtf((float)lcnt[t] + 1.0f);
        }
    }
    if (b == 0 && t == 0) offs[N] = E;
    __syncthreads();
    for (int i = t; i < cnt; i += 256) {
        unsigned p = part[e0 + i];
        int dl = p >> 17;
        int sv = (int)(p & 0x1FFFF);
        int lp = atomicAdd(&lcur[dl], 1);
        if (lp < CAP) stage[lp] = sv;
        else col[e0 + lp] = sv;  // overflow fallback (never for E/N here)
    }
    __syncthreads();
    for (int i = t; i < cnt && i < CAP; i += 256) col[e0 + i] = stage[i];
}

// ---------------- fp32 -> bf16 convert ----------------
__global__ void k_f2b(const float* __restrict__ a, bf16_t* __restrict__ o, int n) {
    int i = blockIdx.x * blockDim.x + threadIdx.x;
    if (i < n) o[i] = (bf16_t)a[i];
}

// ---------------- MFMA GEMM: H[n,m] = sum_k X[n,k]*W[m,k], K=128 ----------------
template <int NCOL, typename TIN>
__global__ __launch_bounds__(256) void k_gemm_mfma(const TIN* __restrict__ X,
                                                   const bf16_t* __restrict__ W,
                                                   bf16_t* __restrict__ H, int N) {
    constexpr int CT = NCOL / 16;
    int wv = threadIdx.x >> 6, lane = threadIdx.x & 63;
    int quad = lane >> 4, l16 = lane & 15;
    int row0 = blockIdx.x * 128 + wv * 32;
    f32x4 acc[2][CT] = {};
#pragma unroll
    for (int ks = 0; ks < 4; ks++) {
        int k0 = ks * 32 + quad * 8;
        bf16x8 a[2];
#pragma unroll
        for (int rt = 0; rt < 2; rt++) {
            int r = row0 + rt * 16 + l16;
            if (r >= N) r = N - 1;  // clamp; stores guarded below
            const TIN* p = X + (size_t)r * 128 + k0;
            if constexpr (sizeof(TIN) == 4) {
                f32x4 x0 = *(const f32x4*)p;
                f32x4 x1 = *(const f32x4*)(p + 4);
                bf16x8 tt;
                tt[0] = (bf16_t)x0[0]; tt[1] = (bf16_t)x0[1];
                tt[2] = (bf16_t)x0[2]; tt[3] = (bf16_t)x0[3];
                tt[4] = (bf16_t)x1[0]; tt[5] = (bf16_t)x1[1];
                tt[6] = (bf16_t)x1[2]; tt[7] = (bf16_t)x1[3];
                a[rt] = tt;
            } else {
                a[rt] = *(const bf16x8*)p;
            }
        }
#pragma unroll
        for (int ct = 0; ct < CT; ct++) {
            bf16x8 bfrag = *(const bf16x8*)(W + (size_t)(ct * 16 + l16) * 128 + k0);
#pragma unroll
            for (int rt = 0; rt < 2; rt++)
                acc[rt][ct] = __builtin_amdgcn_mfma_f32_16x16x32_bf16(a[rt], bfrag, acc[rt][ct], 0, 0, 0);
        }
    }
#pragma unroll
    for (int rt = 0; rt < 2; rt++)
#pragma unroll
        for (int r4 = 0; r4 < 4; r4++) {
            int r = row0 + rt * 16 + quad * 4 + r4;
            if (r < N) {
#pragma unroll
                for (int ct = 0; ct < CT; ct++)
                    H[(size_t)r * NCOL + ct * 16 + l16] = (bf16_t)acc[rt][ct][r4];
            }
        }
}

// ---------------- aggregation: one wave per node, 8-way edge unroll ----------------
template <int F, bool RELU, typename TOUT>
__global__ __launch_bounds__(256) void k_agg(const bf16_t* __restrict__ h,
                                             const int* __restrict__ off,
                                             const int* __restrict__ col,
                                             const float* __restrict__ dinv,
                                             const float* __restrict__ bias,
                                             TOUT* __restrict__ out, int N) {
    constexpr int V = F / 64;
    int wave = threadIdx.x >> 6;
    int lane = threadIdx.x & 63;
    int node = blockIdx.x * 4 + wave;
    if (node >= N) return;
    float di = dinv[node];
    float acc[V];
    {
        const bf16_t* p = h + (size_t)node * F + lane * V;
        if constexpr (V == 2) {
            bf16x2 r = *(const bf16x2*)p;
            acc[0] = di * di * (float)r[0];
            acc[1] = di * di * (float)r[1];
        } else {
            acc[0] = di * di * (float)p[0];
        }
    }
    int e0 = off[node], e1 = off[node + 1];
    int e = e0;
    for (; e + 8 <= e1; e += 8) {
        int s[8];
        float w[8];
#pragma unroll
        for (int u = 0; u < 8; u++) s[u] = col[e + u];
        if constexpr (V == 2) {
            bf16x2 r[8];
#pragma unroll
            for (int u = 0; u < 8; u++) r[u] = *(const bf16x2*)(h + (size_t)s[u] * F + lane * 2);
#pragma unroll
            for (int u = 0; u < 8; u++) w[u] = di * dinv[s[u]];
#pragma unroll
            for (int u = 0; u < 8; u++) {
                acc[0] += w[u] * (float)r[u][0];
                acc[1] += w[u] * (float)r[u][1];
            }
        } else {
            float r[8];
#pragma unroll
            for (int u = 0; u < 8; u++) r[u] = (float)h[(size_t)s[u] * F + lane];
#pragma unroll
            for (int u = 0; u < 8; u++) w[u] = di * dinv[s[u]];
#pragma unroll
            for (int u = 0; u < 8; u++) acc[0] += w[u] * r[u];
        }
    }
    for (; e < e1; e++) {
        int s = col[e];
        float w = di * dinv[s];
        const bf16_t* p = h + (size_t)s * F + lane * V;
        if constexpr (V == 2) {
            bf16x2 r = *(const bf16x2*)p;
            acc[0] += w * (float)r[0];
            acc[1] += w * (float)r[1];
        } else {
            acc[0] += w * (float)p[0];
        }
    }
#pragma unroll
    for (int v = 0; v < V; v++) {
        float r = acc[v] + bias[lane * V + v];
        if (RELU) r = fmaxf(r, 0.f);
        out[(size_t)node * F + lane * V + v] = (TOUT)r;
    }
}

extern "C" void kernel_launch(void* const* d_in, const int* in_sizes, int n_in,
                              void* d_out, int out_size, void* d_ws, size_t ws_size,
                              hipStream_t stream) {
    const float* x  = (const float*)d_in[0];
    const float* W1 = (const float*)d_in[1];
    const float* b1 = (const float*)d_in[2];
    const float* W2 = (const float*)d_in[3];
    const float* b2 = (const float*)d_in[4];
    const int*   ei = (const int*)d_in[5];

    int N = in_sizes[0] / IN_F;
    int E = in_sizes[5] / 2;
    const int* src = ei;
    const int* dst = ei + E;
    int NBKT = (N + NPB - 1) / NPB;  // 782 for N=100000 (<= MAXBKT)

    size_t woff = 0;
    auto alloc = [&](size_t bytes) {
        void* p = (char*)d_ws + woff;
        woff += (bytes + 255) & ~(size_t)255;
        return p;
    };
    int*      bcnt = (int*)alloc((size_t)NBKT * 4);
    int*      boff = (int*)alloc((size_t)(NBKT + 1) * 4);
    int*      bcur = (int*)alloc((size_t)NBKT * 4);
    unsigned* part = (unsigned*)alloc((size_t)E * 4);
    int*      offs = (int*)alloc((size_t)(N + 1) * 4);
    int*      col  = (int*)alloc((size_t)E * 4);
    float*    dinv = (float*)alloc((size_t)N * 4);
    bf16_t*   W1b  = (bf16_t*)alloc((size_t)HID_F * IN_F * 2);
    bf16_t*   W2b  = (bf16_t*)alloc((size_t)OUT_F * HID_F * 2);
    bf16_t*   h1   = (bf16_t*)alloc((size_t)N * HID_F * 2);
    bf16_t*   h1r  = (bf16_t*)alloc((size_t)N * HID_F * 2);
    bf16_t*   h2   = h1;  // h1 dead after agg1
    float*    outp = (float*)d_out;

    hipMemsetAsync(bcnt, 0, (size_t)NBKT * 4, stream);

    // weight conversions (independent of CSR chain)
    k_f2b<<<(HID_F * IN_F + 255) / 256, 256, 0, stream>>>(W1, W1b, HID_F * IN_F);
    k_f2b<<<(OUT_F * HID_F + 255) / 256, 256, 0, stream>>>(W2, W2b, OUT_F * HID_F);

    // CSR build: hist -> scan -> partition -> per-bucket finalize
    int pchunks = (E + CHUNK - 1) / CHUNK;
    k_hist<<<pchunks, 256, 0, stream>>>(dst, E, bcnt, NBKT);
    k_bscan<<<1, 1024, 0, stream>>>(bcnt, boff, bcur, NBKT);
    k_part<<<pchunks, 256, 0, stream>>>(src, dst, E, bcur, part, NBKT);
    k_bucket<<<NBKT, 256, 0, stream>>>(part, boff, offs, col, dinv, N, E);

    int gemm_blocks = (N + 127) / 128;
    int agg_blocks  = (N + 3) / 4;

    // layer 1: GEMM (fp32 x -> bf16 h1), agg (+b1, relu) -> bf16 h1r
    k_gemm_mfma<HID_F, float><<<gemm_blocks, 256, 0, stream>>>(x, W1b, h1, N);
    k_agg<HID_F, true, bf16_t><<<agg_blocks, 256, 0, stream>>>(h1, offs, col, dinv, b1, h1r, N);

    // layer 2: GEMM (bf16 h1r -> bf16 h2), agg (+b2) -> fp32 out
    k_gemm_mfma<OUT_F, bf16_t><<<gemm_blocks, 256, 0, stream>>>(h1r, W2b, h2, N);
    k_agg<OUT_F, false, float><<<agg_blocks, 256, 0, stream>>>(h2, offs, col, dinv, b2, outp, N);
}

// Round 4
// 360.699 us; speedup vs baseline: 1.9237x; 1.0666x over previous
//
#include <hip/hip_runtime.h>
#include <hip/hip_bf16.h>

// GCN 2-layer, N=100000, E=1.6M, 128->128->64.
// Round 4: fold dinv[src] into GEMM epilogue (h' = dinv*h), so the agg
// gather is a pure col->row add chain (no per-edge dinv gather/mult).
// agg64: 2 edges per wave-instruction via half-wave pairing + shfl_xor(32).

#define IN_F  128
#define HID_F 128
#define OUT_F 64

#define NPB     128    // nodes per bucket (dst>>7)
#define MAXBKT  1024
#define CHUNK   16384
#define CAP     4096

typedef __bf16 bf16_t;
typedef __bf16 bf16x2 __attribute__((ext_vector_type(2)));
typedef __bf16 bf16x8 __attribute__((ext_vector_type(8)));
typedef float  f32x4  __attribute__((ext_vector_type(4)));

// ---------------- pass A: bucket histogram ----------------
__global__ __launch_bounds__(256) void k_hist(const int* __restrict__ dst, int E,
                                              int* __restrict__ bcnt, int NBKT) {
    __shared__ int cnt[MAXBKT];
    for (int i = threadIdx.x; i < NBKT; i += 256) cnt[i] = 0;
    __syncthreads();
    int base = blockIdx.x * CHUNK;
    for (int i = threadIdx.x; i < CHUNK; i += 256) {
        int e = base + i;
        if (e < E) atomicAdd(&cnt[dst[e] >> 7], 1);
    }
    __syncthreads();
    for (int i = threadIdx.x; i < NBKT; i += 256)
        if (cnt[i]) atomicAdd(&bcnt[i], cnt[i]);
}

// ---------------- pass B: scan bucket counts (1 block) ----------------
__global__ __launch_bounds__(1024) void k_bscan(const int* __restrict__ bcnt,
                                                int* __restrict__ boff,
                                                int* __restrict__ bcur, int NBKT) {
    __shared__ int s[1024];
    int t = threadIdx.x;
    int v = (t < NBKT) ? bcnt[t] : 0;
    s[t] = v;
    __syncthreads();
    for (int ofs = 1; ofs < 1024; ofs <<= 1) {
        int add = (t >= ofs) ? s[t - ofs] : 0;
        __syncthreads();
        s[t] += add;
        __syncthreads();
    }
    if (t < NBKT) {
        int e = s[t] - v;
        boff[t] = e;
        bcur[t] = e;
    }
    if (t == 1023) boff[NBKT] = s[1023];
}

// ---------------- pass C: partition edges into buckets ----------------
__global__ __launch_bounds__(256) void k_part(const int* __restrict__ src,
                                              const int* __restrict__ dst, int E,
                                              int* __restrict__ bcur,
                                              unsigned* __restrict__ part, int NBKT) {
    __shared__ int cnt[MAXBKT];
    __shared__ int base[MAXBKT];
    for (int i = threadIdx.x; i < NBKT; i += 256) cnt[i] = 0;
    __syncthreads();
    int cbase = blockIdx.x * CHUNK;
    for (int i = threadIdx.x; i < CHUNK; i += 256) {
        int e = cbase + i;
        if (e < E) atomicAdd(&cnt[dst[e] >> 7], 1);
    }
    __syncthreads();
    for (int i = threadIdx.x; i < NBKT; i += 256) {
        int c = cnt[i];
        base[i] = c ? atomicAdd(&bcur[i], c) : 0;
        cnt[i] = 0;
    }
    __syncthreads();
    for (int i = threadIdx.x; i < CHUNK; i += 256) {
        int e = cbase + i;
        if (e < E) {
            int d = dst[e];
            int b = d >> 7;
            int lp = atomicAdd(&cnt[b], 1);
            part[base[b] + lp] = (unsigned)src[e] | ((unsigned)(d & 127) << 17);
        }
    }
}

// ---------------- pass D: per-bucket CSR finalize ----------------
__global__ __launch_bounds__(256) void k_bucket(const unsigned* __restrict__ part,
                                                const int* __restrict__ boff,
                                                int* __restrict__ offs,
                                                int* __restrict__ col,
                                                float* __restrict__ dinv,
                                                int N, int E) {
    __shared__ int lcnt[NPB];
    __shared__ int lexc[NPB];
    __shared__ int lcur[NPB];
    __shared__ int stage[CAP];
    int b = blockIdx.x;
    int t = threadIdx.x;
    int node0 = b * NPB;
    int nb = min(NPB, N - node0);
    int e0 = boff[b], e1 = boff[b + 1];
    int cnt = e1 - e0;
    if (t < NPB) lcnt[t] = 0;
    __syncthreads();
    for (int i = t; i < cnt; i += 256)
        atomicAdd(&lcnt[part[e0 + i] >> 17], 1);
    __syncthreads();
    if (t < NPB) lexc[t] = lcnt[t];
    __syncthreads();
    for (int ofs = 1; ofs < NPB; ofs <<= 1) {
        int add = (t >= ofs && t < NPB) ? lexc[t - ofs] : 0;
        __syncthreads();
        if (t < NPB) lexc[t] += add;
        __syncthreads();
    }
    if (t < NPB) {
        int ex = lexc[t] - lcnt[t];
        lcur[t] = ex;
        if (t < nb) {
            offs[node0 + t] = e0 + ex;
            dinv[node0 + t] = rsqrtf((float)lcnt[t] + 1.0f);
        }
    }
    if (b == 0 && t == 0) offs[N] = E;
    __syncthreads();
    for (int i = t; i < cnt; i += 256) {
        unsigned p = part[e0 + i];
        int dl = p >> 17;
        int sv = (int)(p & 0x1FFFF);
        int lp = atomicAdd(&lcur[dl], 1);
        if (lp < CAP) stage[lp] = sv;
        else col[e0 + lp] = sv;
    }
    __syncthreads();
    for (int i = t; i < cnt && i < CAP; i += 256) col[e0 + i] = stage[i];
}

// ---------------- fp32 -> bf16 convert ----------------
__global__ void k_f2b(const float* __restrict__ a, bf16_t* __restrict__ o, int n) {
    int i = blockIdx.x * blockDim.x + threadIdx.x;
    if (i < n) o[i] = (bf16_t)a[i];
}

// ---------------- MFMA GEMM + row-scale epilogue ----------------
// H[n,m] = scale[n] * sum_k X[n,k]*W[m,k], K=128, H stored bf16.
template <int NCOL, typename TIN>
__global__ __launch_bounds__(256) void k_gemm_mfma(const TIN* __restrict__ X,
                                                   const bf16_t* __restrict__ W,
                                                   const float* __restrict__ scale,
                                                   bf16_t* __restrict__ H, int N) {
    constexpr int CT = NCOL / 16;
    int wv = threadIdx.x >> 6, lane = threadIdx.x & 63;
    int quad = lane >> 4, l16 = lane & 15;
    int row0 = blockIdx.x * 128 + wv * 32;
    f32x4 acc[2][CT] = {};
#pragma unroll
    for (int ks = 0; ks < 4; ks++) {
        int k0 = ks * 32 + quad * 8;
        bf16x8 a[2];
#pragma unroll
        for (int rt = 0; rt < 2; rt++) {
            int r = row0 + rt * 16 + l16;
            if (r >= N) r = N - 1;
            const TIN* p = X + (size_t)r * 128 + k0;
            if constexpr (sizeof(TIN) == 4) {
                f32x4 x0 = *(const f32x4*)p;
                f32x4 x1 = *(const f32x4*)(p + 4);
                bf16x8 tt;
                tt[0] = (bf16_t)x0[0]; tt[1] = (bf16_t)x0[1];
                tt[2] = (bf16_t)x0[2]; tt[3] = (bf16_t)x0[3];
                tt[4] = (bf16_t)x1[0]; tt[5] = (bf16_t)x1[1];
                tt[6] = (bf16_t)x1[2]; tt[7] = (bf16_t)x1[3];
                a[rt] = tt;
            } else {
                a[rt] = *(const bf16x8*)p;
            }
        }
#pragma unroll
        for (int ct = 0; ct < CT; ct++) {
            bf16x8 bfrag = *(const bf16x8*)(W + (size_t)(ct * 16 + l16) * 128 + k0);
#pragma unroll
            for (int rt = 0; rt < 2; rt++)
                acc[rt][ct] = __builtin_amdgcn_mfma_f32_16x16x32_bf16(a[rt], bfrag, acc[rt][ct], 0, 0, 0);
        }
    }
#pragma unroll
    for (int rt = 0; rt < 2; rt++)
#pragma unroll
        for (int r4 = 0; r4 < 4; r4++) {
            int r = row0 + rt * 16 + quad * 4 + r4;
            if (r < N) {
                float sc = scale[r];
#pragma unroll
                for (int ct = 0; ct < CT; ct++)
                    H[(size_t)r * NCOL + ct * 16 + l16] = (bf16_t)(sc * acc[rt][ct][r4]);
            }
        }
}

// ---------------- agg, F=128: wave/node, lane = 2 features, 8-way unroll ----
// h is pre-scaled by dinv[src]. out[i] = di * (h[i] + sum h[col]) + bias.
template <bool RELU, typename TOUT>
__global__ __launch_bounds__(256) void k_agg128(const bf16_t* __restrict__ h,
                                                const int* __restrict__ off,
                                                const int* __restrict__ col,
                                                const float* __restrict__ dinv,
                                                const float* __restrict__ bias,
                                                TOUT* __restrict__ out, int N) {
    int wave = threadIdx.x >> 6;
    int lane = threadIdx.x & 63;
    int node = blockIdx.x * 4 + wave;
    if (node >= N) return;
    int f = lane * 2;
    float a0, a1;
    {
        bf16x2 r = *(const bf16x2*)(h + (size_t)node * 128 + f);
        a0 = (float)r[0]; a1 = (float)r[1];
    }
    int e0 = off[node], e1 = off[node + 1];
    int e = e0;
    for (; e + 8 <= e1; e += 8) {
        int s[8];
#pragma unroll
        for (int u = 0; u < 8; u++) s[u] = col[e + u];
        bf16x2 r[8];
#pragma unroll
        for (int u = 0; u < 8; u++) r[u] = *(const bf16x2*)(h + (size_t)s[u] * 128 + f);
#pragma unroll
        for (int u = 0; u < 8; u++) { a0 += (float)r[u][0]; a1 += (float)r[u][1]; }
    }
    for (; e < e1; e++) {
        int s = col[e];
        bf16x2 r = *(const bf16x2*)(h + (size_t)s * 128 + f);
        a0 += (float)r[0]; a1 += (float)r[1];
    }
    float di = dinv[node];
    float r0 = a0 * di + bias[f];
    float r1 = a1 * di + bias[f + 1];
    if (RELU) { r0 = fmaxf(r0, 0.f); r1 = fmaxf(r1, 0.f); }
    if constexpr (sizeof(TOUT) == 2) {
        bf16x2 v; v[0] = (bf16_t)r0; v[1] = (bf16_t)r1;
        *(bf16x2*)((bf16_t*)out + (size_t)node * 128 + f) = v;
    } else {
        float2 v = make_float2(r0, r1);
        *(float2*)((float*)out + (size_t)node * 128 + f) = v;
    }
}

// ---------------- agg, F=64: wave/node, half-wave = one edge --------------
// lane handles features {2*(lane&31), +1} of edge e + (lane>>5).
template <bool RELU>
__global__ __launch_bounds__(256) void k_agg64(const bf16_t* __restrict__ h,
                                               const int* __restrict__ off,
                                               const int* __restrict__ col,
                                               const float* __restrict__ dinv,
                                               const float* __restrict__ bias,
                                               float* __restrict__ out, int N) {
    int wave = threadIdx.x >> 6;
    int lane = threadIdx.x & 63;
    int node = blockIdx.x * 4 + wave;
    if (node >= N) return;
    int p = lane >> 5;
    int f = (lane & 31) * 2;
    float a0 = 0.f, a1 = 0.f;
    if (p == 0) {
        bf16x2 r = *(const bf16x2*)(h + (size_t)node * 64 + f);
        a0 = (float)r[0]; a1 = (float)r[1];
    }
    int e0 = off[node], e1 = off[node + 1];
    int e = e0;
    for (; e + 8 <= e1; e += 8) {
        int s[4];
#pragma unroll
        for (int u = 0; u < 4; u++) s[u] = col[e + 2 * u + p];
        bf16x2 r[4];
#pragma unroll
        for (int u = 0; u < 4; u++) r[u] = *(const bf16x2*)(h + (size_t)s[u] * 64 + f);
#pragma unroll
        for (int u = 0; u < 4; u++) { a0 += (float)r[u][0]; a1 += (float)r[u][1]; }
    }
    for (; e + 2 <= e1; e += 2) {
        int s = col[e + p];
        bf16x2 r = *(const bf16x2*)(h + (size_t)s * 64 + f);
        a0 += (float)r[0]; a1 += (float)r[1];
    }
    if (e < e1 && p == 0) {
        int s = col[e];
        bf16x2 r = *(const bf16x2*)(h + (size_t)s * 64 + f);
        a0 += (float)r[0]; a1 += (float)r[1];
    }
    a0 += __shfl_xor(a0, 32);
    a1 += __shfl_xor(a1, 32);
    if (p == 0) {
        float di = dinv[node];
        float r0 = a0 * di + bias[f];
        float r1 = a1 * di + bias[f + 1];
        if (RELU) { r0 = fmaxf(r0, 0.f); r1 = fmaxf(r1, 0.f); }
        *(float2*)(out + (size_t)node * 64 + f) = make_float2(r0, r1);
    }
}

extern "C" void kernel_launch(void* const* d_in, const int* in_sizes, int n_in,
                              void* d_out, int out_size, void* d_ws, size_t ws_size,
                              hipStream_t stream) {
    const float* x  = (const float*)d_in[0];
    const float* W1 = (const float*)d_in[1];
    const float* b1 = (const float*)d_in[2];
    const float* W2 = (const float*)d_in[3];
    const float* b2 = (const float*)d_in[4];
    const int*   ei = (const int*)d_in[5];

    int N = in_sizes[0] / IN_F;
    int E = in_sizes[5] / 2;
    const int* src = ei;
    const int* dst = ei + E;
    int NBKT = (N + NPB - 1) / NPB;

    size_t woff = 0;
    auto alloc = [&](size_t bytes) {
        void* p = (char*)d_ws + woff;
        woff += (bytes + 255) & ~(size_t)255;
        return p;
    };
    int*      bcnt = (int*)alloc((size_t)NBKT * 4);
    int*      boff = (int*)alloc((size_t)(NBKT + 1) * 4);
    int*      bcur = (int*)alloc((size_t)NBKT * 4);
    unsigned* part = (unsigned*)alloc((size_t)E * 4);
    int*      offs = (int*)alloc((size_t)(N + 1) * 4);
    int*      col  = (int*)alloc((size_t)E * 4);
    float*    dinv = (float*)alloc((size_t)N * 4);
    bf16_t*   W1b  = (bf16_t*)alloc((size_t)HID_F * IN_F * 2);
    bf16_t*   W2b  = (bf16_t*)alloc((size_t)OUT_F * HID_F * 2);
    bf16_t*   h1   = (bf16_t*)alloc((size_t)N * HID_F * 2);
    bf16_t*   h1r  = (bf16_t*)alloc((size_t)N * HID_F * 2);
    bf16_t*   h2   = h1;  // h1 dead after agg1
    float*    outp = (float*)d_out;

    hipMemsetAsync(bcnt, 0, (size_t)NBKT * 4, stream);

    k_f2b<<<(HID_F * IN_F + 255) / 256, 256, 0, stream>>>(W1, W1b, HID_F * IN_F);
    k_f2b<<<(OUT_F * HID_F + 255) / 256, 256, 0, stream>>>(W2, W2b, OUT_F * HID_F);

    int pchunks = (E + CHUNK - 1) / CHUNK;
    k_hist<<<pchunks, 256, 0, stream>>>(dst, E, bcnt, NBKT);
    k_bscan<<<1, 1024, 0, stream>>>(bcnt, boff, bcur, NBKT);
    k_part<<<pchunks, 256, 0, stream>>>(src, dst, E, bcur, part, NBKT);
    k_bucket<<<NBKT, 256, 0, stream>>>(part, boff, offs, col, dinv, N, E);

    int gemm_blocks = (N + 127) / 128;
    int agg_blocks  = (N + 3) / 4;

    // layer 1: h1 = dinv * (x@W1^T)  [bf16]; agg -> relu -> h1r [bf16]
    k_gemm_mfma<HID_F, float><<<gemm_blocks, 256, 0, stream>>>(x, W1b, dinv, h1, N);
    k_agg128<true, bf16_t><<<agg_blocks, 256, 0, stream>>>(h1, offs, col, dinv, b1, h1r, N);

    // layer 2: h2 = dinv * (h1r@W2^T) [bf16]; agg -> fp32 out
    k_gemm_mfma<OUT_F, bf16_t><<<gemm_blocks, 256, 0, stream>>>(h1r, W2b, dinv, h2, N);
    k_agg64<false><<<agg_blocks, 256, 0, stream>>>(h2, offs, col, dinv, b2, outp, N);
}

// Round 5
// 343.535 us; speedup vs baseline: 2.0198x; 1.0500x over previous
//
#include <hip/hip_runtime.h>
#include <hip/hip_bf16.h>

// GCN 2-layer, N=100000, E=1.6M, 128->128->64.
// Round 5: CHUNK 16384->2048 in hist/part (98 -> 782 workgroups).
// R4's k_part ran at 3.3% occupancy / 1.1% VALU — pure latency starvation.

#define IN_F  128
#define HID_F 128
#define OUT_F 64

#define NPB     128    // nodes per bucket (dst>>7)
#define MAXBKT  1024
#define CHUNK   2048   // edges per workgroup in hist/part (782 blocks)
#define CAP     4096

typedef __bf16 bf16_t;
typedef __bf16 bf16x2 __attribute__((ext_vector_type(2)));
typedef __bf16 bf16x8 __attribute__((ext_vector_type(8)));
typedef float  f32x4  __attribute__((ext_vector_type(4)));

// ---------------- pass A: bucket histogram ----------------
__global__ __launch_bounds__(256) void k_hist(const int* __restrict__ dst, int E,
                                              int* __restrict__ bcnt, int NBKT) {
    __shared__ int cnt[MAXBKT];
    for (int i = threadIdx.x; i < NBKT; i += 256) cnt[i] = 0;
    __syncthreads();
    int base = blockIdx.x * CHUNK;
    for (int i = threadIdx.x; i < CHUNK; i += 256) {
        int e = base + i;
        if (e < E) atomicAdd(&cnt[dst[e] >> 7], 1);
    }
    __syncthreads();
    for (int i = threadIdx.x; i < NBKT; i += 256)
        if (cnt[i]) atomicAdd(&bcnt[i], cnt[i]);
}

// ---------------- pass B: scan bucket counts (1 block) ----------------
__global__ __launch_bounds__(1024) void k_bscan(const int* __restrict__ bcnt,
                                                int* __restrict__ boff,
                                                int* __restrict__ bcur, int NBKT) {
    __shared__ int s[1024];
    int t = threadIdx.x;
    int v = (t < NBKT) ? bcnt[t] : 0;
    s[t] = v;
    __syncthreads();
    for (int ofs = 1; ofs < 1024; ofs <<= 1) {
        int add = (t >= ofs) ? s[t - ofs] : 0;
        __syncthreads();
        s[t] += add;
        __syncthreads();
    }
    if (t < NBKT) {
        int e = s[t] - v;
        boff[t] = e;
        bcur[t] = e;
    }
    if (t == 1023) boff[NBKT] = s[1023];
}

// ---------------- pass C: partition edges into buckets ----------------
// packed = (dst&127)<<17 | src
__global__ __launch_bounds__(256) void k_part(const int* __restrict__ src,
                                              const int* __restrict__ dst, int E,
                                              int* __restrict__ bcur,
                                              unsigned* __restrict__ part, int NBKT) {
    __shared__ int cnt[MAXBKT];
    __shared__ int base[MAXBKT];
    for (int i = threadIdx.x; i < NBKT; i += 256) cnt[i] = 0;
    __syncthreads();
    int cbase = blockIdx.x * CHUNK;
    for (int i = threadIdx.x; i < CHUNK; i += 256) {
        int e = cbase + i;
        if (e < E) atomicAdd(&cnt[dst[e] >> 7], 1);
    }
    __syncthreads();
    for (int i = threadIdx.x; i < NBKT; i += 256) {
        int c = cnt[i];
        base[i] = c ? atomicAdd(&bcur[i], c) : 0;
        cnt[i] = 0;
    }
    __syncthreads();
    for (int i = threadIdx.x; i < CHUNK; i += 256) {
        int e = cbase + i;
        if (e < E) {
            int d = dst[e];
            int b = d >> 7;
            int lp = atomicAdd(&cnt[b], 1);
            part[base[b] + lp] = (unsigned)src[e] | ((unsigned)(d & 127) << 17);
        }
    }
}

// ---------------- pass D: per-bucket CSR finalize ----------------
__global__ __launch_bounds__(256) void k_bucket(const unsigned* __restrict__ part,
                                                const int* __restrict__ boff,
                                                int* __restrict__ offs,
                                                int* __restrict__ col,
                                                float* __restrict__ dinv,
                                                int N, int E) {
    __shared__ int lcnt[NPB];
    __shared__ int lexc[NPB];
    __shared__ int lcur[NPB];
    __shared__ int stage[CAP];
    int b = blockIdx.x;
    int t = threadIdx.x;
    int node0 = b * NPB;
    int nb = min(NPB, N - node0);
    int e0 = boff[b], e1 = boff[b + 1];
    int cnt = e1 - e0;
    if (t < NPB) lcnt[t] = 0;
    __syncthreads();
    for (int i = t; i < cnt; i += 256)
        atomicAdd(&lcnt[part[e0 + i] >> 17], 1);
    __syncthreads();
    if (t < NPB) lexc[t] = lcnt[t];
    __syncthreads();
    for (int ofs = 1; ofs < NPB; ofs <<= 1) {
        int add = (t >= ofs && t < NPB) ? lexc[t - ofs] : 0;
        __syncthreads();
        if (t < NPB) lexc[t] += add;
        __syncthreads();
    }
    if (t < NPB) {
        int ex = lexc[t] - lcnt[t];
        lcur[t] = ex;
        if (t < nb) {
            offs[node0 + t] = e0 + ex;
            dinv[node0 + t] = rsqrtf((float)lcnt[t] + 1.0f);
        }
    }
    if (b == 0 && t == 0) offs[N] = E;
    __syncthreads();
    for (int i = t; i < cnt; i += 256) {
        unsigned p = part[e0 + i];
        int dl = p >> 17;
        int sv = (int)(p & 0x1FFFF);
        int lp = atomicAdd(&lcur[dl], 1);
        if (lp < CAP) stage[lp] = sv;
        else col[e0 + lp] = sv;
    }
    __syncthreads();
    for (int i = t; i < cnt && i < CAP; i += 256) col[e0 + i] = stage[i];
}

// ---------------- fp32 -> bf16 convert ----------------
__global__ void k_f2b(const float* __restrict__ a, bf16_t* __restrict__ o, int n) {
    int i = blockIdx.x * blockDim.x + threadIdx.x;
    if (i < n) o[i] = (bf16_t)a[i];
}

// ---------------- MFMA GEMM + row-scale epilogue ----------------
// H[n,m] = scale[n] * sum_k X[n,k]*W[m,k], K=128, H stored bf16.
template <int NCOL, typename TIN>
__global__ __launch_bounds__(256) void k_gemm_mfma(const TIN* __restrict__ X,
                                                   const bf16_t* __restrict__ W,
                                                   const float* __restrict__ scale,
                                                   bf16_t* __restrict__ H, int N) {
    constexpr int CT = NCOL / 16;
    int wv = threadIdx.x >> 6, lane = threadIdx.x & 63;
    int quad = lane >> 4, l16 = lane & 15;
    int row0 = blockIdx.x * 128 + wv * 32;
    f32x4 acc[2][CT] = {};
#pragma unroll
    for (int ks = 0; ks < 4; ks++) {
        int k0 = ks * 32 + quad * 8;
        bf16x8 a[2];
#pragma unroll
        for (int rt = 0; rt < 2; rt++) {
            int r = row0 + rt * 16 + l16;
            if (r >= N) r = N - 1;
            const TIN* p = X + (size_t)r * 128 + k0;
            if constexpr (sizeof(TIN) == 4) {
                f32x4 x0 = *(const f32x4*)p;
                f32x4 x1 = *(const f32x4*)(p + 4);
                bf16x8 tt;
                tt[0] = (bf16_t)x0[0]; tt[1] = (bf16_t)x0[1];
                tt[2] = (bf16_t)x0[2]; tt[3] = (bf16_t)x0[3];
                tt[4] = (bf16_t)x1[0]; tt[5] = (bf16_t)x1[1];
                tt[6] = (bf16_t)x1[2]; tt[7] = (bf16_t)x1[3];
                a[rt] = tt;
            } else {
                a[rt] = *(const bf16x8*)p;
            }
        }
#pragma unroll
        for (int ct = 0; ct < CT; ct++) {
            bf16x8 bfrag = *(const bf16x8*)(W + (size_t)(ct * 16 + l16) * 128 + k0);
#pragma unroll
            for (int rt = 0; rt < 2; rt++)
                acc[rt][ct] = __builtin_amdgcn_mfma_f32_16x16x32_bf16(a[rt], bfrag, acc[rt][ct], 0, 0, 0);
        }
    }
#pragma unroll
    for (int rt = 0; rt < 2; rt++)
#pragma unroll
        for (int r4 = 0; r4 < 4; r4++) {
            int r = row0 + rt * 16 + quad * 4 + r4;
            if (r < N) {
                float sc = scale[r];
#pragma unroll
                for (int ct = 0; ct < CT; ct++)
                    H[(size_t)r * NCOL + ct * 16 + l16] = (bf16_t)(sc * acc[rt][ct][r4]);
            }
        }
}

// ---------------- agg, F=128: wave/node, lane = 2 features, 8-way unroll ----
template <bool RELU, typename TOUT>
__global__ __launch_bounds__(256) void k_agg128(const bf16_t* __restrict__ h,
                                                const int* __restrict__ off,
                                                const int* __restrict__ col,
                                                const float* __restrict__ dinv,
                                                const float* __restrict__ bias,
                                                TOUT* __restrict__ out, int N) {
    int wave = threadIdx.x >> 6;
    int lane = threadIdx.x & 63;
    int node = blockIdx.x * 4 + wave;
    if (node >= N) return;
    int f = lane * 2;
    float a0, a1;
    {
        bf16x2 r = *(const bf16x2*)(h + (size_t)node * 128 + f);
        a0 = (float)r[0]; a1 = (float)r[1];
    }
    int e0 = off[node], e1 = off[node + 1];
    int e = e0;
    for (; e + 8 <= e1; e += 8) {
        int s[8];
#pragma unroll
        for (int u = 0; u < 8; u++) s[u] = col[e + u];
        bf16x2 r[8];
#pragma unroll
        for (int u = 0; u < 8; u++) r[u] = *(const bf16x2*)(h + (size_t)s[u] * 128 + f);
#pragma unroll
        for (int u = 0; u < 8; u++) { a0 += (float)r[u][0]; a1 += (float)r[u][1]; }
    }
    for (; e < e1; e++) {
        int s = col[e];
        bf16x2 r = *(const bf16x2*)(h + (size_t)s * 128 + f);
        a0 += (float)r[0]; a1 += (float)r[1];
    }
    float di = dinv[node];
    float r0 = a0 * di + bias[f];
    float r1 = a1 * di + bias[f + 1];
    if (RELU) { r0 = fmaxf(r0, 0.f); r1 = fmaxf(r1, 0.f); }
    if constexpr (sizeof(TOUT) == 2) {
        bf16x2 v; v[0] = (bf16_t)r0; v[1] = (bf16_t)r1;
        *(bf16x2*)((bf16_t*)out + (size_t)node * 128 + f) = v;
    } else {
        float2 v = make_float2(r0, r1);
        *(float2*)((float*)out + (size_t)node * 128 + f) = v;
    }
}

// ---------------- agg, F=64: wave/node, half-wave = one edge --------------
template <bool RELU>
__global__ __launch_bounds__(256) void k_agg64(const bf16_t* __restrict__ h,
                                               const int* __restrict__ off,
                                               const int* __restrict__ col,
                                               const float* __restrict__ dinv,
                                               const float* __restrict__ bias,
                                               float* __restrict__ out, int N) {
    int wave = threadIdx.x >> 6;
    int lane = threadIdx.x & 63;
    int node = blockIdx.x * 4 + wave;
    if (node >= N) return;
    int p = lane >> 5;
    int f = (lane & 31) * 2;
    float a0 = 0.f, a1 = 0.f;
    if (p == 0) {
        bf16x2 r = *(const bf16x2*)(h + (size_t)node * 64 + f);
        a0 = (float)r[0]; a1 = (float)r[1];
    }
    int e0 = off[node], e1 = off[node + 1];
    int e = e0;
    for (; e + 8 <= e1; e += 8) {
        int s[4];
#pragma unroll
        for (int u = 0; u < 4; u++) s[u] = col[e + 2 * u + p];
        bf16x2 r[4];
#pragma unroll
        for (int u = 0; u < 4; u++) r[u] = *(const bf16x2*)(h + (size_t)s[u] * 64 + f);
#pragma unroll
        for (int u = 0; u < 4; u++) { a0 += (float)r[u][0]; a1 += (float)r[u][1]; }
    }
    for (; e + 2 <= e1; e += 2) {
        int s = col[e + p];
        bf16x2 r = *(const bf16x2*)(h + (size_t)s * 64 + f);
        a0 += (float)r[0]; a1 += (float)r[1];
    }
    if (e < e1 && p == 0) {
        int s = col[e];
        bf16x2 r = *(const bf16x2*)(h + (size_t)s * 64 + f);
        a0 += (float)r[0]; a1 += (float)r[1];
    }
    a0 += __shfl_xor(a0, 32);
    a1 += __shfl_xor(a1, 32);
    if (p == 0) {
        float di = dinv[node];
        float r0 = a0 * di + bias[f];
        float r1 = a1 * di + bias[f + 1];
        if (RELU) { r0 = fmaxf(r0, 0.f); r1 = fmaxf(r1, 0.f); }
        *(float2*)(out + (size_t)node * 64 + f) = make_float2(r0, r1);
    }
}

extern "C" void kernel_launch(void* const* d_in, const int* in_sizes, int n_in,
                              void* d_out, int out_size, void* d_ws, size_t ws_size,
                              hipStream_t stream) {
    const float* x  = (const float*)d_in[0];
    const float* W1 = (const float*)d_in[1];
    const float* b1 = (const float*)d_in[2];
    const float* W2 = (const float*)d_in[3];
    const float* b2 = (const float*)d_in[4];
    const int*   ei = (const int*)d_in[5];

    int N = in_sizes[0] / IN_F;
    int E = in_sizes[5] / 2;
    const int* src = ei;
    const int* dst = ei + E;
    int NBKT = (N + NPB - 1) / NPB;

    size_t woff = 0;
    auto alloc = [&](size_t bytes) {
        void* p = (char*)d_ws + woff;
        woff += (bytes + 255) & ~(size_t)255;
        return p;
    };
    int*      bcnt = (int*)alloc((size_t)NBKT * 4);
    int*      boff = (int*)alloc((size_t)(NBKT + 1) * 4);
    int*      bcur = (int*)alloc((size_t)NBKT * 4);
    unsigned* part = (unsigned*)alloc((size_t)E * 4);
    int*      offs = (int*)alloc((size_t)(N + 1) * 4);
    int*      col  = (int*)alloc((size_t)E * 4);
    float*    dinv = (float*)alloc((size_t)N * 4);
    bf16_t*   W1b  = (bf16_t*)alloc((size_t)HID_F * IN_F * 2);
    bf16_t*   W2b  = (bf16_t*)alloc((size_t)OUT_F * HID_F * 2);
    bf16_t*   h1   = (bf16_t*)alloc((size_t)N * HID_F * 2);
    bf16_t*   h1r  = (bf16_t*)alloc((size_t)N * HID_F * 2);
    bf16_t*   h2   = h1;  // h1 dead after agg1
    float*    outp = (float*)d_out;

    hipMemsetAsync(bcnt, 0, (size_t)NBKT * 4, stream);

    k_f2b<<<(HID_F * IN_F + 255) / 256, 256, 0, stream>>>(W1, W1b, HID_F * IN_F);
    k_f2b<<<(OUT_F * HID_F + 255) / 256, 256, 0, stream>>>(W2, W2b, OUT_F * HID_F);

    int pchunks = (E + CHUNK - 1) / CHUNK;
    k_hist<<<pchunks, 256, 0, stream>>>(dst, E, bcnt, NBKT);
    k_bscan<<<1, 1024, 0, stream>>>(bcnt, boff, bcur, NBKT);
    k_part<<<pchunks, 256, 0, stream>>>(src, dst, E, bcur, part, NBKT);
    k_bucket<<<NBKT, 256, 0, stream>>>(part, boff, offs, col, dinv, N, E);

    int gemm_blocks = (N + 127) / 128;
    int agg_blocks  = (N + 3) / 4;

    // layer 1: h1 = dinv * (x@W1^T)  [bf16]; agg -> relu -> h1r [bf16]
    k_gemm_mfma<HID_F, float><<<gemm_blocks, 256, 0, stream>>>(x, W1b, dinv, h1, N);
    k_agg128<true, bf16_t><<<agg_blocks, 256, 0, stream>>>(h1, offs, col, dinv, b1, h1r, N);

    // layer 2: h2 = dinv * (h1r@W2^T) [bf16]; agg -> fp32 out
    k_gemm_mfma<OUT_F, bf16_t><<<gemm_blocks, 256, 0, stream>>>(h1r, W2b, dinv, h2, N);
    k_agg64<false><<<agg_blocks, 256, 0, stream>>>(h2, offs, col, dinv, b2, outp, N);
}

// Round 6
// 337.750 us; speedup vs baseline: 2.0544x; 1.0171x over previous
//
#include <hip/hip_runtime.h>
#include <hip/hip_bf16.h>

// GCN 2-layer, N=100000, E=1.6M, 128->128->64.
// Round 6: multi-edge-per-wave agg (bf16x4 per lane; agg128 = 2 edges/instr
// via half-wave split, agg64 = 4 edges/instr via quarter-wave split),
// k_part reuses k_hist's chunk histograms (drops its counting pass),
// merged f2b launches.

#define IN_F  128
#define HID_F 128
#define OUT_F 64

#define NPB     128    // nodes per bucket (dst>>7)
#define MAXBKT  1024
#define CHUNK   2048   // edges per workgroup in hist/part
#define CAP     4096

typedef __bf16 bf16_t;
typedef __bf16 bf16x2 __attribute__((ext_vector_type(2)));
typedef __bf16 bf16x4 __attribute__((ext_vector_type(4)));
typedef __bf16 bf16x8 __attribute__((ext_vector_type(8)));
typedef float  f32x4  __attribute__((ext_vector_type(4)));

// ---------------- pass A: bucket histogram (+ per-chunk hist stash) --------
__global__ __launch_bounds__(256) void k_hist(const int* __restrict__ dst, int E,
                                              int* __restrict__ bcnt,
                                              int* __restrict__ chunkhist, int NBKT) {
    __shared__ int cnt[MAXBKT];
    for (int i = threadIdx.x; i < NBKT; i += 256) cnt[i] = 0;
    __syncthreads();
    int base = blockIdx.x * CHUNK;
    for (int i = threadIdx.x; i < CHUNK; i += 256) {
        int e = base + i;
        if (e < E) atomicAdd(&cnt[dst[e] >> 7], 1);
    }
    __syncthreads();
    int* ch = chunkhist + (size_t)blockIdx.x * MAXBKT;
    for (int i = threadIdx.x; i < NBKT; i += 256) {
        int c = cnt[i];
        ch[i] = c;
        if (c) atomicAdd(&bcnt[i], c);
    }
}

// ---------------- pass B: scan bucket counts (1 block) ----------------
__global__ __launch_bounds__(1024) void k_bscan(const int* __restrict__ bcnt,
                                                int* __restrict__ boff,
                                                int* __restrict__ bcur, int NBKT) {
    __shared__ int s[1024];
    int t = threadIdx.x;
    int v = (t < NBKT) ? bcnt[t] : 0;
    s[t] = v;
    __syncthreads();
    for (int ofs = 1; ofs < 1024; ofs <<= 1) {
        int add = (t >= ofs) ? s[t - ofs] : 0;
        __syncthreads();
        s[t] += add;
        __syncthreads();
    }
    if (t < NBKT) {
        int e = s[t] - v;
        boff[t] = e;
        bcur[t] = e;
    }
    if (t == 1023) boff[NBKT] = s[1023];
}

// ---------------- pass C: partition edges into buckets ----------------
// packed = (dst&127)<<17 | src ; counting pass replaced by chunkhist reuse.
__global__ __launch_bounds__(256) void k_part(const int* __restrict__ src,
                                              const int* __restrict__ dst, int E,
                                              int* __restrict__ bcur,
                                              const int* __restrict__ chunkhist,
                                              unsigned* __restrict__ part, int NBKT) {
    __shared__ int cnt[MAXBKT];
    __shared__ int base[MAXBKT];
    const int* ch = chunkhist + (size_t)blockIdx.x * MAXBKT;
    for (int i = threadIdx.x; i < NBKT; i += 256) {
        int c = ch[i];
        base[i] = c ? atomicAdd(&bcur[i], c) : 0;
        cnt[i] = 0;
    }
    __syncthreads();
    int cbase = blockIdx.x * CHUNK;
    for (int i = threadIdx.x; i < CHUNK; i += 256) {
        int e = cbase + i;
        if (e < E) {
            int d = dst[e];
            int b = d >> 7;
            int lp = atomicAdd(&cnt[b], 1);
            part[base[b] + lp] = (unsigned)src[e] | ((unsigned)(d & 127) << 17);
        }
    }
}

// ---------------- pass D: per-bucket CSR finalize ----------------
__global__ __launch_bounds__(256) void k_bucket(const unsigned* __restrict__ part,
                                                const int* __restrict__ boff,
                                                int* __restrict__ offs,
                                                int* __restrict__ col,
                                                float* __restrict__ dinv,
                                                int N, int E) {
    __shared__ int lcnt[NPB];
    __shared__ int lexc[NPB];
    __shared__ int lcur[NPB];
    __shared__ int stage[CAP];
    int b = blockIdx.x;
    int t = threadIdx.x;
    int node0 = b * NPB;
    int nb = min(NPB, N - node0);
    int e0 = boff[b], e1 = boff[b + 1];
    int cnt = e1 - e0;
    if (t < NPB) lcnt[t] = 0;
    __syncthreads();
    for (int i = t; i < cnt; i += 256)
        atomicAdd(&lcnt[part[e0 + i] >> 17], 1);
    __syncthreads();
    if (t < NPB) lexc[t] = lcnt[t];
    __syncthreads();
    for (int ofs = 1; ofs < NPB; ofs <<= 1) {
        int add = (t >= ofs && t < NPB) ? lexc[t - ofs] : 0;
        __syncthreads();
        if (t < NPB) lexc[t] += add;
        __syncthreads();
    }
    if (t < NPB) {
        int ex = lexc[t] - lcnt[t];
        lcur[t] = ex;
        if (t < nb) {
            offs[node0 + t] = e0 + ex;
            dinv[node0 + t] = rsqrtf((float)lcnt[t] + 1.0f);
        }
    }
    if (b == 0 && t == 0) offs[N] = E;
    __syncthreads();
    for (int i = t; i < cnt; i += 256) {
        unsigned p = part[e0 + i];
        int dl = p >> 17;
        int sv = (int)(p & 0x1FFFF);
        int lp = atomicAdd(&lcur[dl], 1);
        if (lp < CAP) stage[lp] = sv;
        else col[e0 + lp] = sv;
    }
    __syncthreads();
    for (int i = t; i < cnt && i < CAP; i += 256) col[e0 + i] = stage[i];
}

// ---------------- fp32 -> bf16 convert (both weights, one launch) ----------
__global__ void k_f2b2(const float* __restrict__ a1, bf16_t* __restrict__ o1, int n1,
                       const float* __restrict__ a2, bf16_t* __restrict__ o2, int n2) {
    int i = blockIdx.x * blockDim.x + threadIdx.x;
    if (i < n1) o1[i] = (bf16_t)a1[i];
    else if (i < n1 + n2) o2[i - n1] = (bf16_t)a2[i - n1];
}

// ---------------- MFMA GEMM + row-scale epilogue ----------------
// H[n,m] = scale[n] * sum_k X[n,k]*W[m,k], K=128, H stored bf16.
template <int NCOL, typename TIN>
__global__ __launch_bounds__(256) void k_gemm_mfma(const TIN* __restrict__ X,
                                                   const bf16_t* __restrict__ W,
                                                   const float* __restrict__ scale,
                                                   bf16_t* __restrict__ H, int N) {
    constexpr int CT = NCOL / 16;
    int wv = threadIdx.x >> 6, lane = threadIdx.x & 63;
    int quad = lane >> 4, l16 = lane & 15;
    int row0 = blockIdx.x * 128 + wv * 32;
    f32x4 acc[2][CT] = {};
#pragma unroll
    for (int ks = 0; ks < 4; ks++) {
        int k0 = ks * 32 + quad * 8;
        bf16x8 a[2];
#pragma unroll
        for (int rt = 0; rt < 2; rt++) {
            int r = row0 + rt * 16 + l16;
            if (r >= N) r = N - 1;
            const TIN* p = X + (size_t)r * 128 + k0;
            if constexpr (sizeof(TIN) == 4) {
                f32x4 x0 = *(const f32x4*)p;
                f32x4 x1 = *(const f32x4*)(p + 4);
                bf16x8 tt;
                tt[0] = (bf16_t)x0[0]; tt[1] = (bf16_t)x0[1];
                tt[2] = (bf16_t)x0[2]; tt[3] = (bf16_t)x0[3];
                tt[4] = (bf16_t)x1[0]; tt[5] = (bf16_t)x1[1];
                tt[6] = (bf16_t)x1[2]; tt[7] = (bf16_t)x1[3];
                a[rt] = tt;
            } else {
                a[rt] = *(const bf16x8*)p;
            }
        }
#pragma unroll
        for (int ct = 0; ct < CT; ct++) {
            bf16x8 bfrag = *(const bf16x8*)(W + (size_t)(ct * 16 + l16) * 128 + k0);
#pragma unroll
            for (int rt = 0; rt < 2; rt++)
                acc[rt][ct] = __builtin_amdgcn_mfma_f32_16x16x32_bf16(a[rt], bfrag, acc[rt][ct], 0, 0, 0);
        }
    }
#pragma unroll
    for (int rt = 0; rt < 2; rt++)
#pragma unroll
        for (int r4 = 0; r4 < 4; r4++) {
            int r = row0 + rt * 16 + quad * 4 + r4;
            if (r < N) {
                float sc = scale[r];
#pragma unroll
                for (int ct = 0; ct < CT; ct++)
                    H[(size_t)r * NCOL + ct * 16 + l16] = (bf16_t)(sc * acc[rt][ct][r4]);
            }
        }
}

// ---------------- agg, F=128: wave/node, half-wave = one edge --------------
// lane: p = lane>>5 (edge parity), f = (lane&31)*4 (feature quad).
// h pre-scaled by dinv[src]; out = di*(h[i] + sum h[col]) + bias.
template <bool RELU, typename TOUT>
__global__ __launch_bounds__(256) void k_agg128(const bf16_t* __restrict__ h,
                                                const int* __restrict__ off,
                                                const int* __restrict__ col,
                                                const float* __restrict__ dinv,
                                                const float* __restrict__ bias,
                                                TOUT* __restrict__ out, int N) {
    int wave = threadIdx.x >> 6;
    int lane = threadIdx.x & 63;
    int node = blockIdx.x * 4 + wave;
    if (node >= N) return;
    int p = lane >> 5;
    int f = (lane & 31) * 4;
    float a0 = 0.f, a1 = 0.f, a2 = 0.f, a3 = 0.f;
    if (p == 0) {
        bf16x4 r = *(const bf16x4*)(h + (unsigned)node * 128u + f);
        a0 = (float)r[0]; a1 = (float)r[1]; a2 = (float)r[2]; a3 = (float)r[3];
    }
    int e0 = off[node], e1 = off[node + 1];
    int e = e0;
    for (; e + 8 <= e1; e += 8) {
        int s[4];
#pragma unroll
        for (int u = 0; u < 4; u++) s[u] = col[e + 2 * u + p];
        bf16x4 r[4];
#pragma unroll
        for (int u = 0; u < 4; u++) r[u] = *(const bf16x4*)(h + (unsigned)s[u] * 128u + f);
#pragma unroll
        for (int u = 0; u < 4; u++) {
            a0 += (float)r[u][0]; a1 += (float)r[u][1];
            a2 += (float)r[u][2]; a3 += (float)r[u][3];
        }
    }
    for (; e < e1; e += 2) {
        int idx = e + p;
        if (idx < e1) {
            bf16x4 r = *(const bf16x4*)(h + (unsigned)col[idx] * 128u + f);
            a0 += (float)r[0]; a1 += (float)r[1];
            a2 += (float)r[2]; a3 += (float)r[3];
        }
    }
    a0 += __shfl_xor(a0, 32);
    a1 += __shfl_xor(a1, 32);
    a2 += __shfl_xor(a2, 32);
    a3 += __shfl_xor(a3, 32);
    if (p == 0) {
        float di = dinv[node];
        f32x4 bv = *(const f32x4*)(bias + f);
        float r0 = a0 * di + bv[0];
        float r1 = a1 * di + bv[1];
        float r2 = a2 * di + bv[2];
        float r3 = a3 * di + bv[3];
        if (RELU) {
            r0 = fmaxf(r0, 0.f); r1 = fmaxf(r1, 0.f);
            r2 = fmaxf(r2, 0.f); r3 = fmaxf(r3, 0.f);
        }
        if constexpr (sizeof(TOUT) == 2) {
            bf16x4 v;
            v[0] = (bf16_t)r0; v[1] = (bf16_t)r1; v[2] = (bf16_t)r2; v[3] = (bf16_t)r3;
            *(bf16x4*)((bf16_t*)out + (unsigned)node * 128u + f) = v;
        } else {
            f32x4 v = {r0, r1, r2, r3};
            *(f32x4*)((float*)out + (unsigned)node * 128u + f) = v;
        }
    }
}

// ---------------- agg, F=64: wave/node, quarter-wave = one edge ------------
// lane: q = lane>>4 (edge slot 0..3), f = (lane&15)*4.
template <bool RELU>
__global__ __launch_bounds__(256) void k_agg64(const bf16_t* __restrict__ h,
                                               const int* __restrict__ off,
                                               const int* __restrict__ col,
                                               const float* __restrict__ dinv,
                                               const float* __restrict__ bias,
                                               float* __restrict__ out, int N) {
    int wave = threadIdx.x >> 6;
    int lane = threadIdx.x & 63;
    int node = blockIdx.x * 4 + wave;
    if (node >= N) return;
    int q = lane >> 4;
    int f = (lane & 15) * 4;
    float a0 = 0.f, a1 = 0.f, a2 = 0.f, a3 = 0.f;
    if (q == 0) {
        bf16x4 r = *(const bf16x4*)(h + (unsigned)node * 64u + f);
        a0 = (float)r[0]; a1 = (float)r[1]; a2 = (float)r[2]; a3 = (float)r[3];
    }
    int e0 = off[node], e1 = off[node + 1];
    int e = e0;
    for (; e + 8 <= e1; e += 8) {
        int s0 = col[e + q], s1 = col[e + 4 + q];
        bf16x4 r0 = *(const bf16x4*)(h + (unsigned)s0 * 64u + f);
        bf16x4 r1 = *(const bf16x4*)(h + (unsigned)s1 * 64u + f);
        a0 += (float)r0[0] + (float)r1[0];
        a1 += (float)r0[1] + (float)r1[1];
        a2 += (float)r0[2] + (float)r1[2];
        a3 += (float)r0[3] + (float)r1[3];
    }
    for (; e < e1; e += 4) {
        int idx = e + q;
        if (idx < e1) {
            bf16x4 r = *(const bf16x4*)(h + (unsigned)col[idx] * 64u + f);
            a0 += (float)r[0]; a1 += (float)r[1];
            a2 += (float)r[2]; a3 += (float)r[3];
        }
    }
    a0 += __shfl_xor(a0, 16); a0 += __shfl_xor(a0, 32);
    a1 += __shfl_xor(a1, 16); a1 += __shfl_xor(a1, 32);
    a2 += __shfl_xor(a2, 16); a2 += __shfl_xor(a2, 32);
    a3 += __shfl_xor(a3, 16); a3 += __shfl_xor(a3, 32);
    if (lane < 16) {
        float di = dinv[node];
        f32x4 bv = *(const f32x4*)(bias + f);
        float r0 = a0 * di + bv[0];
        float r1 = a1 * di + bv[1];
        float r2 = a2 * di + bv[2];
        float r3 = a3 * di + bv[3];
        if (RELU) {
            r0 = fmaxf(r0, 0.f); r1 = fmaxf(r1, 0.f);
            r2 = fmaxf(r2, 0.f); r3 = fmaxf(r3, 0.f);
        }
        f32x4 v = {r0, r1, r2, r3};
        *(f32x4*)(out + (unsigned)node * 64u + f) = v;
    }
}

extern "C" void kernel_launch(void* const* d_in, const int* in_sizes, int n_in,
                              void* d_out, int out_size, void* d_ws, size_t ws_size,
                              hipStream_t stream) {
    const float* x  = (const float*)d_in[0];
    const float* W1 = (const float*)d_in[1];
    const float* b1 = (const float*)d_in[2];
    const float* W2 = (const float*)d_in[3];
    const float* b2 = (const float*)d_in[4];
    const int*   ei = (const int*)d_in[5];

    int N = in_sizes[0] / IN_F;
    int E = in_sizes[5] / 2;
    const int* src = ei;
    const int* dst = ei + E;
    int NBKT = (N + NPB - 1) / NPB;
    int pchunks = (E + CHUNK - 1) / CHUNK;

    size_t woff = 0;
    auto alloc = [&](size_t bytes) {
        void* p = (char*)d_ws + woff;
        woff += (bytes + 255) & ~(size_t)255;
        return p;
    };
    int*      bcnt  = (int*)alloc((size_t)NBKT * 4);
    int*      boff  = (int*)alloc((size_t)(NBKT + 1) * 4);
    int*      bcur  = (int*)alloc((size_t)NBKT * 4);
    int*      chist = (int*)alloc((size_t)pchunks * MAXBKT * 4);
    unsigned* part  = (unsigned*)alloc((size_t)E * 4);
    int*      offs  = (int*)alloc((size_t)(N + 1) * 4);
    int*      col   = (int*)alloc((size_t)E * 4);
    float*    dinv  = (float*)alloc((size_t)N * 4);
    bf16_t*   W1b   = (bf16_t*)alloc((size_t)HID_F * IN_F * 2);
    bf16_t*   W2b   = (bf16_t*)alloc((size_t)OUT_F * HID_F * 2);
    bf16_t*   h1    = (bf16_t*)alloc((size_t)N * HID_F * 2);
    bf16_t*   h1r   = (bf16_t*)alloc((size_t)N * HID_F * 2);
    bf16_t*   h2    = h1;  // h1 dead after agg1
    float*    outp  = (float*)d_out;

    hipMemsetAsync(bcnt, 0, (size_t)NBKT * 4, stream);

    int nW = HID_F * IN_F + OUT_F * HID_F;
    k_f2b2<<<(nW + 255) / 256, 256, 0, stream>>>(W1, W1b, HID_F * IN_F, W2, W2b, OUT_F * HID_F);

    k_hist<<<pchunks, 256, 0, stream>>>(dst, E, bcnt, chist, NBKT);
    k_bscan<<<1, 1024, 0, stream>>>(bcnt, boff, bcur, NBKT);
    k_part<<<pchunks, 256, 0, stream>>>(src, dst, E, bcur, chist, part, NBKT);
    k_bucket<<<NBKT, 256, 0, stream>>>(part, boff, offs, col, dinv, N, E);

    int gemm_blocks = (N + 127) / 128;
    int agg_blocks  = (N + 3) / 4;

    // layer 1: h1 = dinv * (x@W1^T)  [bf16]; agg -> relu -> h1r [bf16]
    k_gemm_mfma<HID_F, float><<<gemm_blocks, 256, 0, stream>>>(x, W1b, dinv, h1, N);
    k_agg128<true, bf16_t><<<agg_blocks, 256, 0, stream>>>(h1, offs, col, dinv, b1, h1r, N);

    // layer 2: h2 = dinv * (h1r@W2^T) [bf16]; agg -> fp32 out
    k_gemm_mfma<OUT_F, bf16_t><<<gemm_blocks, 256, 0, stream>>>(h1r, W2b, dinv, h2, N);
    k_agg64<false><<<agg_blocks, 256, 0, stream>>>(h2, offs, col, dinv, b2, outp, N);
}

// Round 8
// 331.547 us; speedup vs baseline: 2.0928x; 1.0187x over previous
//
#include <hip/hip_runtime.h>
#include <hip/hip_bf16.h>

// GCN 2-layer, N=100000, E=1.6M, 128->128->64.
// Round 8: R7 + fix — W1/W2 are separate allocations; the merged f2b tail
// must read from both pointers (R7 read nW floats from W1 alone -> garbage W2b).

#define IN_F  128
#define HID_F 128
#define OUT_F 64

#define NPB     256    // nodes per bucket (dst>>8)
#define MAXBKT  512    // >= NBKT = ceil(N/256) = 391
#define CHUNK   2048   // edges per workgroup in hist/part
#define CAP     8192   // col staging capacity per bucket (mean ~4092)

typedef __bf16 bf16_t;
typedef __bf16 bf16x4 __attribute__((ext_vector_type(4)));
typedef __bf16 bf16x8 __attribute__((ext_vector_type(8)));
typedef float  f32x4  __attribute__((ext_vector_type(4)));

// ---------------- pass A: bucket histogram + chunk stash + weight f2b ------
__global__ __launch_bounds__(256) void k_hist(const int* __restrict__ dst, int E,
                                              int* __restrict__ bcnt,
                                              int* __restrict__ chunkhist, int NBKT,
                                              int pchunks,
                                              const float* __restrict__ W1s,
                                              const float* __restrict__ W2s,
                                              bf16_t* __restrict__ Wdst,
                                              int n1, int n2) {
    if ((int)blockIdx.x >= pchunks) {
        // weight conversion tail blocks (W1 then W2, separate pointers!)
        int i = (blockIdx.x - pchunks) * 256 + threadIdx.x;
        if (i < n1) Wdst[i] = (bf16_t)W1s[i];
        else if (i < n1 + n2) Wdst[i] = (bf16_t)W2s[i - n1];
        return;
    }
    __shared__ int cnt[MAXBKT];
    for (int i = threadIdx.x; i < NBKT; i += 256) cnt[i] = 0;
    __syncthreads();
    int base = blockIdx.x * CHUNK;
    for (int i = threadIdx.x; i < CHUNK; i += 256) {
        int e = base + i;
        if (e < E) atomicAdd(&cnt[dst[e] >> 8], 1);
    }
    __syncthreads();
    int* ch = chunkhist + (size_t)blockIdx.x * MAXBKT;
    for (int i = threadIdx.x; i < NBKT; i += 256) {
        int c = cnt[i];
        ch[i] = c;
        if (c) atomicAdd(&bcnt[i], c);
    }
}

// ---------------- pass B: scan bucket counts (1 block) ----------------
__global__ __launch_bounds__(512) void k_bscan(const int* __restrict__ bcnt,
                                               int* __restrict__ boff,
                                               int* __restrict__ bcur, int NBKT) {
    __shared__ int s[512];
    int t = threadIdx.x;
    int v = (t < NBKT) ? bcnt[t] : 0;
    s[t] = v;
    __syncthreads();
    for (int ofs = 1; ofs < 512; ofs <<= 1) {
        int add = (t >= ofs) ? s[t - ofs] : 0;
        __syncthreads();
        s[t] += add;
        __syncthreads();
    }
    if (t < NBKT) {
        int e = s[t] - v;
        boff[t] = e;
        bcur[t] = e;
    }
    if (t == 511) boff[NBKT] = s[511];
}

// ---------------- pass C: partition edges into buckets ----------------
// packed = (dst&255)<<17 | src  (src < 2^17 since N <= 131072)
__global__ __launch_bounds__(256) void k_part(const int* __restrict__ src,
                                              const int* __restrict__ dst, int E,
                                              int* __restrict__ bcur,
                                              const int* __restrict__ chunkhist,
                                              unsigned* __restrict__ part, int NBKT) {
    __shared__ int cnt[MAXBKT];
    __shared__ int base[MAXBKT];
    const int* ch = chunkhist + (size_t)blockIdx.x * MAXBKT;
    for (int i = threadIdx.x; i < NBKT; i += 256) {
        int c = ch[i];
        base[i] = c ? atomicAdd(&bcur[i], c) : 0;
        cnt[i] = 0;
    }
    __syncthreads();
    int cbase = blockIdx.x * CHUNK;
    for (int i = threadIdx.x; i < CHUNK; i += 256) {
        int e = cbase + i;
        if (e < E) {
            int d = dst[e];
            int b = d >> 8;
            int lp = atomicAdd(&cnt[b], 1);
            part[base[b] + lp] = (unsigned)src[e] | ((unsigned)(d & 255) << 17);
        }
    }
}

// ---------------- pass D: per-bucket CSR finalize ----------------
__global__ __launch_bounds__(512) void k_bucket(const unsigned* __restrict__ part,
                                                const int* __restrict__ boff,
                                                int* __restrict__ offs,
                                                int* __restrict__ col,
                                                float* __restrict__ dinv,
                                                int N, int E) {
    __shared__ int lcnt[NPB];
    __shared__ int lexc[NPB];
    __shared__ int lcur[NPB];
    __shared__ int stage[CAP];
    int b = blockIdx.x;
    int t = threadIdx.x;
    int node0 = b * NPB;
    int nb = min(NPB, N - node0);
    int e0 = boff[b], e1 = boff[b + 1];
    int cnt = e1 - e0;
    if (t < NPB) lcnt[t] = 0;
    __syncthreads();
    for (int i = t; i < cnt; i += 512)
        atomicAdd(&lcnt[part[e0 + i] >> 17], 1);
    __syncthreads();
    if (t < NPB) lexc[t] = lcnt[t];
    __syncthreads();
    for (int ofs = 1; ofs < NPB; ofs <<= 1) {
        int add = (t >= ofs && t < NPB) ? lexc[t - ofs] : 0;
        __syncthreads();
        if (t < NPB) lexc[t] += add;
        __syncthreads();
    }
    if (t < NPB) {
        int ex = lexc[t] - lcnt[t];
        lcur[t] = ex;
        if (t < nb) {
            offs[node0 + t] = e0 + ex;
            dinv[node0 + t] = rsqrtf((float)lcnt[t] + 1.0f);
        }
    }
    if (b == 0 && t == 0) offs[N] = E;
    __syncthreads();
    for (int i = t; i < cnt; i += 512) {
        unsigned p = part[e0 + i];
        int dl = p >> 17;
        int sv = (int)(p & 0x1FFFF);
        int lp = atomicAdd(&lcur[dl], 1);
        if (lp < CAP) stage[lp] = sv;
        else col[e0 + lp] = sv;  // statistically unreachable overflow path
    }
    __syncthreads();
    for (int i = t; i < cnt && i < CAP; i += 512) col[e0 + i] = stage[i];
}

// ---------------- MFMA GEMM + row-scale epilogue ----------------
// H[n,m] = scale[n] * sum_k X[n,k]*W[m,k], K=128, H stored bf16.
template <int NCOL, typename TIN>
__global__ __launch_bounds__(256) void k_gemm_mfma(const TIN* __restrict__ X,
                                                   const bf16_t* __restrict__ W,
                                                   const float* __restrict__ scale,
                                                   bf16_t* __restrict__ H, int N) {
    constexpr int CT = NCOL / 16;
    int wv = threadIdx.x >> 6, lane = threadIdx.x & 63;
    int quad = lane >> 4, l16 = lane & 15;
    int row0 = blockIdx.x * 128 + wv * 32;
    f32x4 acc[2][CT] = {};
#pragma unroll
    for (int ks = 0; ks < 4; ks++) {
        int k0 = ks * 32 + quad * 8;
        bf16x8 a[2];
#pragma unroll
        for (int rt = 0; rt < 2; rt++) {
            int r = row0 + rt * 16 + l16;
            if (r >= N) r = N - 1;
            const TIN* p = X + (size_t)r * 128 + k0;
            if constexpr (sizeof(TIN) == 4) {
                f32x4 x0 = *(const f32x4*)p;
                f32x4 x1 = *(const f32x4*)(p + 4);
                bf16x8 tt;
                tt[0] = (bf16_t)x0[0]; tt[1] = (bf16_t)x0[1];
                tt[2] = (bf16_t)x0[2]; tt[3] = (bf16_t)x0[3];
                tt[4] = (bf16_t)x1[0]; tt[5] = (bf16_t)x1[1];
                tt[6] = (bf16_t)x1[2]; tt[7] = (bf16_t)x1[3];
                a[rt] = tt;
            } else {
                a[rt] = *(const bf16x8*)p;
            }
        }
#pragma unroll
        for (int ct = 0; ct < CT; ct++) {
            bf16x8 bfrag = *(const bf16x8*)(W + (size_t)(ct * 16 + l16) * 128 + k0);
#pragma unroll
            for (int rt = 0; rt < 2; rt++)
                acc[rt][ct] = __builtin_amdgcn_mfma_f32_16x16x32_bf16(a[rt], bfrag, acc[rt][ct], 0, 0, 0);
        }
    }
#pragma unroll
    for (int rt = 0; rt < 2; rt++)
#pragma unroll
        for (int r4 = 0; r4 < 4; r4++) {
            int r = row0 + rt * 16 + quad * 4 + r4;
            if (r < N) {
                float sc = scale[r];
#pragma unroll
                for (int ct = 0; ct < CT; ct++)
                    H[(size_t)r * NCOL + ct * 16 + l16] = (bf16_t)(sc * acc[rt][ct][r4]);
            }
        }
}

// ---------------- agg, F=128: wave/node, quarter-wave = one edge ----------
// lane: q = lane>>4 (edge slot 0..3), f = (lane&15)*8 (feature octet).
// h pre-scaled by dinv[src]; out = di*(h[i] + sum h[col]) + bias.
template <bool RELU, typename TOUT>
__global__ __launch_bounds__(256) void k_agg128(const bf16_t* __restrict__ h,
                                                const int* __restrict__ off,
                                                const int* __restrict__ col,
                                                const float* __restrict__ dinv,
                                                const float* __restrict__ bias,
                                                TOUT* __restrict__ out, int N) {
    int wave = threadIdx.x >> 6;
    int lane = threadIdx.x & 63;
    int node = blockIdx.x * 4 + wave;
    if (node >= N) return;
    int q = lane >> 4;
    int f = (lane & 15) * 8;
    float a[8] = {0.f, 0.f, 0.f, 0.f, 0.f, 0.f, 0.f, 0.f};
    if (q == 0) {
        bf16x8 r = *(const bf16x8*)(h + (unsigned)node * 128u + f);
#pragma unroll
        for (int j = 0; j < 8; j++) a[j] = (float)r[j];
    }
    int e0 = off[node], e1 = off[node + 1];
    int e = e0;
    for (; e + 8 <= e1; e += 8) {
        int s0 = col[e + q], s1 = col[e + 4 + q];
        bf16x8 r0 = *(const bf16x8*)(h + (unsigned)s0 * 128u + f);
        bf16x8 r1 = *(const bf16x8*)(h + (unsigned)s1 * 128u + f);
#pragma unroll
        for (int j = 0; j < 8; j++) a[j] += (float)r0[j] + (float)r1[j];
    }
    for (; e < e1; e += 4) {
        int idx = e + q;
        if (idx < e1) {
            bf16x8 r = *(const bf16x8*)(h + (unsigned)col[idx] * 128u + f);
#pragma unroll
            for (int j = 0; j < 8; j++) a[j] += (float)r[j];
        }
    }
#pragma unroll
    for (int j = 0; j < 8; j++) {
        a[j] += __shfl_xor(a[j], 16);
        a[j] += __shfl_xor(a[j], 32);
    }
    if (lane < 16) {
        float di = dinv[node];
        f32x4 b0 = *(const f32x4*)(bias + f);
        f32x4 b1 = *(const f32x4*)(bias + f + 4);
        float r[8];
#pragma unroll
        for (int j = 0; j < 4; j++) r[j] = a[j] * di + b0[j];
#pragma unroll
        for (int j = 0; j < 4; j++) r[4 + j] = a[4 + j] * di + b1[j];
        if (RELU) {
#pragma unroll
            for (int j = 0; j < 8; j++) r[j] = fmaxf(r[j], 0.f);
        }
        if constexpr (sizeof(TOUT) == 2) {
            bf16x8 v;
#pragma unroll
            for (int j = 0; j < 8; j++) v[j] = (bf16_t)r[j];
            *(bf16x8*)((bf16_t*)out + (unsigned)node * 128u + f) = v;
        } else {
            f32x4 v0 = {r[0], r[1], r[2], r[3]};
            f32x4 v1 = {r[4], r[5], r[6], r[7]};
            *(f32x4*)((float*)out + (unsigned)node * 128u + f) = v0;
            *(f32x4*)((float*)out + (unsigned)node * 128u + f + 4) = v1;
        }
    }
}

// ---------------- agg, F=64: wave/node, quarter-wave = one edge -----------
// lane: q = lane>>4 (edge slot 0..3), f = (lane&15)*4. 16-edge unroll.
template <bool RELU>
__global__ __launch_bounds__(256) void k_agg64(const bf16_t* __restrict__ h,
                                               const int* __restrict__ off,
                                               const int* __restrict__ col,
                                               const float* __restrict__ dinv,
                                               const float* __restrict__ bias,
                                               float* __restrict__ out, int N) {
    int wave = threadIdx.x >> 6;
    int lane = threadIdx.x & 63;
    int node = blockIdx.x * 4 + wave;
    if (node >= N) return;
    int q = lane >> 4;
    int f = (lane & 15) * 4;
    float a0 = 0.f, a1 = 0.f, a2 = 0.f, a3 = 0.f;
    if (q == 0) {
        bf16x4 r = *(const bf16x4*)(h + (unsigned)node * 64u + f);
        a0 = (float)r[0]; a1 = (float)r[1]; a2 = (float)r[2]; a3 = (float)r[3];
    }
    int e0 = off[node], e1 = off[node + 1];
    int e = e0;
    for (; e + 16 <= e1; e += 16) {
        int s0 = col[e + q], s1 = col[e + 4 + q];
        int s2 = col[e + 8 + q], s3 = col[e + 12 + q];
        bf16x4 r0 = *(const bf16x4*)(h + (unsigned)s0 * 64u + f);
        bf16x4 r1 = *(const bf16x4*)(h + (unsigned)s1 * 64u + f);
        bf16x4 r2 = *(const bf16x4*)(h + (unsigned)s2 * 64u + f);
        bf16x4 r3 = *(const bf16x4*)(h + (unsigned)s3 * 64u + f);
        a0 += (float)r0[0] + (float)r1[0] + (float)r2[0] + (float)r3[0];
        a1 += (float)r0[1] + (float)r1[1] + (float)r2[1] + (float)r3[1];
        a2 += (float)r0[2] + (float)r1[2] + (float)r2[2] + (float)r3[2];
        a3 += (float)r0[3] + (float)r1[3] + (float)r2[3] + (float)r3[3];
    }
    for (; e < e1; e += 4) {
        int idx = e + q;
        if (idx < e1) {
            bf16x4 r = *(const bf16x4*)(h + (unsigned)col[idx] * 64u + f);
            a0 += (float)r[0]; a1 += (float)r[1];
            a2 += (float)r[2]; a3 += (float)r[3];
        }
    }
    a0 += __shfl_xor(a0, 16); a0 += __shfl_xor(a0, 32);
    a1 += __shfl_xor(a1, 16); a1 += __shfl_xor(a1, 32);
    a2 += __shfl_xor(a2, 16); a2 += __shfl_xor(a2, 32);
    a3 += __shfl_xor(a3, 16); a3 += __shfl_xor(a3, 32);
    if (lane < 16) {
        float di = dinv[node];
        f32x4 bv = *(const f32x4*)(bias + f);
        float r0 = a0 * di + bv[0];
        float r1 = a1 * di + bv[1];
        float r2 = a2 * di + bv[2];
        float r3 = a3 * di + bv[3];
        if (RELU) {
            r0 = fmaxf(r0, 0.f); r1 = fmaxf(r1, 0.f);
            r2 = fmaxf(r2, 0.f); r3 = fmaxf(r3, 0.f);
        }
        f32x4 v = {r0, r1, r2, r3};
        *(f32x4*)(out + (unsigned)node * 64u + f) = v;
    }
}

extern "C" void kernel_launch(void* const* d_in, const int* in_sizes, int n_in,
                              void* d_out, int out_size, void* d_ws, size_t ws_size,
                              hipStream_t stream) {
    const float* x  = (const float*)d_in[0];
    const float* W1 = (const float*)d_in[1];
    const float* b1 = (const float*)d_in[2];
    const float* W2 = (const float*)d_in[3];
    const float* b2 = (const float*)d_in[4];
    const int*   ei = (const int*)d_in[5];

    int N = in_sizes[0] / IN_F;
    int E = in_sizes[5] / 2;
    const int* src = ei;
    const int* dst = ei + E;
    int NBKT = (N + NPB - 1) / NPB;           // 391
    int pchunks = (E + CHUNK - 1) / CHUNK;    // 782

    size_t woff = 0;
    auto alloc = [&](size_t bytes) {
        void* p = (char*)d_ws + woff;
        woff += (bytes + 255) & ~(size_t)255;
        return p;
    };
    int*      bcnt  = (int*)alloc((size_t)NBKT * 4);
    int*      boff  = (int*)alloc((size_t)(NBKT + 1) * 4);
    int*      bcur  = (int*)alloc((size_t)NBKT * 4);
    int*      chist = (int*)alloc((size_t)pchunks * MAXBKT * 4);
    unsigned* part  = (unsigned*)alloc((size_t)E * 4);
    int*      offs  = (int*)alloc((size_t)(N + 1) * 4);
    int*      col   = (int*)alloc((size_t)E * 4);
    float*    dinv  = (float*)alloc((size_t)N * 4);
    bf16_t*   Wb    = (bf16_t*)alloc((size_t)(HID_F * IN_F + OUT_F * HID_F) * 2);
    bf16_t*   W1b   = Wb;
    bf16_t*   W2b   = Wb + HID_F * IN_F;
    bf16_t*   h1    = (bf16_t*)alloc((size_t)N * HID_F * 2);
    bf16_t*   h1r   = (bf16_t*)alloc((size_t)N * HID_F * 2);
    bf16_t*   h2    = h1;  // h1 dead after agg1
    float*    outp  = (float*)d_out;

    hipMemsetAsync(bcnt, 0, (size_t)NBKT * 4, stream);

    int n1 = HID_F * IN_F, n2 = OUT_F * HID_F;
    int wblocks = (n1 + n2 + 255) / 256;
    k_hist<<<pchunks + wblocks, 256, 0, stream>>>(dst, E, bcnt, chist, NBKT,
                                                  pchunks, W1, W2, Wb, n1, n2);
    k_bscan<<<1, 512, 0, stream>>>(bcnt, boff, bcur, NBKT);
    k_part<<<pchunks, 256, 0, stream>>>(src, dst, E, bcur, chist, part, NBKT);
    k_bucket<<<NBKT, 512, 0, stream>>>(part, boff, offs, col, dinv, N, E);

    int gemm_blocks = (N + 127) / 128;
    int agg_blocks  = (N + 3) / 4;

    // layer 1: h1 = dinv * (x@W1^T)  [bf16]; agg -> relu -> h1r [bf16]
    k_gemm_mfma<HID_F, float><<<gemm_blocks, 256, 0, stream>>>(x, W1b, dinv, h1, N);
    k_agg128<true, bf16_t><<<agg_blocks, 256, 0, stream>>>(h1, offs, col, dinv, b1, h1r, N);

    // layer 2: h2 = dinv * (h1r@W2^T) [bf16]; agg -> fp32 out
    k_gemm_mfma<OUT_F, bf16_t><<<gemm_blocks, 256, 0, stream>>>(h1r, W2b, dinv, h2, N);
    k_agg64<false><<<agg_blocks, 256, 0, stream>>>(h2, offs, col, dinv, b2, outp, N);
}